// Round 1
// baseline (2813.549 us; speedup 1.0000x reference)
//
#include <hip/hip_runtime.h>

#define BATCH 8
#define C     64
#define H     128
#define WD    128
#define C3    192
#define HW    (H*WD)
#define LS    68          // LDS row stride for 64x64 chunk tiles (68%32=4 -> 2-way max)

// ---------------------------------------------------------------------------
// Attention kernel: one block per (b,h). 256 threads.
// Computes xp = Wx@x+bx, x1 = Wx1@xp, x2 = Wx2@xp, xfp = Wxf@xf, xrp = Wxr@xr,
// score1 = x1 . xfp^T (over w), feature_xf = score1 @ xp (and same for r),
// writing features into feat (B,128,H,W): ch 0..63 = xf branch, 64..127 = xr.
// W is processed in two 64-wide chunks; scores accumulate in registers.
// LDS: 3 buffers of 64x68 f32 = 52.2 KB.
// ---------------------------------------------------------------------------

// matvec from GLOBAL source slice (rows c stride HW), result chunk -> LDS [o][w]
__device__ __forceinline__ void matvecG(const float* __restrict__ Wm, const float* __restrict__ bias,
                                        const float* __restrict__ gsrc, float* __restrict__ dst, int t)
{
    int o = t >> 2;              // 0..63
    int q = (t & 3) << 2;        // 0,4,8,12 ; thread's w = q + 16k + comp, k=0..3
    float bv = bias[o];
    float acc[4][4];
#pragma unroll
    for (int k = 0; k < 4; ++k) { acc[k][0]=bv; acc[k][1]=bv; acc[k][2]=bv; acc[k][3]=bv; }
    const float* wrow = Wm + o*C;
    for (int c = 0; c < C; ++c) {
        float wgt = wrow[c];
        const float* row = gsrc + (size_t)c*HW + q;
#pragma unroll
        for (int k = 0; k < 4; ++k) {
            float4 v = *(const float4*)(row + 16*k);
            acc[k][0] += wgt*v.x; acc[k][1] += wgt*v.y; acc[k][2] += wgt*v.z; acc[k][3] += wgt*v.w;
        }
    }
#pragma unroll
    for (int k = 0; k < 4; ++k)
        *(float4*)(dst + o*LS + q + 16*k) = make_float4(acc[k][0],acc[k][1],acc[k][2],acc[k][3]);
}

// matvec from GLOBAL source, result chunk stored TRANSPOSED -> LDS [w][o]
__device__ __forceinline__ void matvecGT(const float* __restrict__ Wm, const float* __restrict__ bias,
                                         const float* __restrict__ gsrc, float* __restrict__ dstT, int t)
{
    int o = t >> 2;
    int q = (t & 3) << 2;
    float bv = bias[o];
    float acc[4][4];
#pragma unroll
    for (int k = 0; k < 4; ++k) { acc[k][0]=bv; acc[k][1]=bv; acc[k][2]=bv; acc[k][3]=bv; }
    const float* wrow = Wm + o*C;
    for (int c = 0; c < C; ++c) {
        float wgt = wrow[c];
        const float* row = gsrc + (size_t)c*HW + q;
#pragma unroll
        for (int k = 0; k < 4; ++k) {
            float4 v = *(const float4*)(row + 16*k);
            acc[k][0] += wgt*v.x; acc[k][1] += wgt*v.y; acc[k][2] += wgt*v.z; acc[k][3] += wgt*v.w;
        }
    }
#pragma unroll
    for (int k = 0; k < 4; ++k) {
        int wb = q + 16*k;
        dstT[(wb+0)*LS + o] = acc[k][0];
        dstT[(wb+1)*LS + o] = acc[k][1];
        dstT[(wb+2)*LS + o] = acc[k][2];
        dstT[(wb+3)*LS + o] = acc[k][3];
    }
}

// matvec from LDS source chunk [c][w] -> LDS dst [o][w]
__device__ __forceinline__ void matvecL(const float* __restrict__ Wm, const float* __restrict__ bias,
                                        const float* __restrict__ src, float* __restrict__ dst, int t)
{
    int o = t >> 2;
    int q = (t & 3) << 2;
    float bv = bias[o];
    float acc[4][4];
#pragma unroll
    for (int k = 0; k < 4; ++k) { acc[k][0]=bv; acc[k][1]=bv; acc[k][2]=bv; acc[k][3]=bv; }
    const float* wrow = Wm + o*C;
    for (int c = 0; c < C; ++c) {
        float wgt = wrow[c];
        const float* row = src + c*LS + q;
#pragma unroll
        for (int k = 0; k < 4; ++k) {
            float4 v = *(const float4*)(row + 16*k);
            acc[k][0] += wgt*v.x; acc[k][1] += wgt*v.y; acc[k][2] += wgt*v.z; acc[k][3] += wgt*v.w;
        }
    }
#pragma unroll
    for (int k = 0; k < 4; ++k)
        *(float4*)(dst + o*LS + q + 16*k) = make_float4(acc[k][0],acc[k][1],acc[k][2],acc[k][3]);
}

// score += A[c][w-chunk] . B^T[w-chunk][d]; each thread owns a 4x4 (c,d) tile
__device__ __forceinline__ void score_accum(const float* __restrict__ sA, const float* __restrict__ sBT,
                                            float* __restrict__ acc, int t)
{
    int c0 = (t >> 4) << 2;   // 0..60
    int d0 = (t & 15) << 2;   // 0..60
    for (int w4 = 0; w4 < 16; ++w4) {
        int w = w4 << 2;
        float4 a[4];
#pragma unroll
        for (int i = 0; i < 4; ++i) a[i] = *(const float4*)(sA + (c0+i)*LS + w);
#pragma unroll
        for (int dw = 0; dw < 4; ++dw) {
            float4 bb = *(const float4*)(sBT + (w+dw)*LS + d0);
#pragma unroll
            for (int i = 0; i < 4; ++i) {
                float av = (dw==0)?a[i].x:(dw==1)?a[i].y:(dw==2)?a[i].z:a[i].w;
                acc[i*4+0] += av*bb.x; acc[i*4+1] += av*bb.y;
                acc[i*4+2] += av*bb.z; acc[i*4+3] += av*bb.w;
            }
        }
    }
}

__device__ __forceinline__ void store_score(const float* __restrict__ acc, float* __restrict__ sS, int t)
{
    int c0 = (t >> 4) << 2;
    int d0 = (t & 15) << 2;
#pragma unroll
    for (int i = 0; i < 4; ++i)
        *(float4*)(sS + (c0+i)*LS + d0) = make_float4(acc[i*4+0],acc[i*4+1],acc[i*4+2],acc[i*4+3]);
}

// feature chunk: out[c][w] = sum_d score[c][d] * xp[d][w] -> global
__device__ __forceinline__ void feat_chunk(const float* __restrict__ sS, const float* __restrict__ sXPc,
                                           float* __restrict__ outg, int t)
{
    int o = t >> 2;
    int q = (t & 3) << 2;
    float acc[4][4];
#pragma unroll
    for (int k = 0; k < 4; ++k) { acc[k][0]=0.f; acc[k][1]=0.f; acc[k][2]=0.f; acc[k][3]=0.f; }
    for (int d = 0; d < C; ++d) {
        float s = sS[o*LS + d];
        const float* row = sXPc + d*LS + q;
#pragma unroll
        for (int k = 0; k < 4; ++k) {
            float4 v = *(const float4*)(row + 16*k);
            acc[k][0] += s*v.x; acc[k][1] += s*v.y; acc[k][2] += s*v.z; acc[k][3] += s*v.w;
        }
    }
#pragma unroll
    for (int k = 0; k < 4; ++k)
        *(float4*)(outg + (size_t)o*HW + q + 16*k) = make_float4(acc[k][0],acc[k][1],acc[k][2],acc[k][3]);
}

__global__ __launch_bounds__(256) void attn_kernel(
    const float* __restrict__ x,  const float* __restrict__ xf, const float* __restrict__ xr,
    const float* __restrict__ Wx,  const float* __restrict__ bx,
    const float* __restrict__ Wx1, const float* __restrict__ bx1,
    const float* __restrict__ Wx2, const float* __restrict__ bx2,
    const float* __restrict__ Wxf, const float* __restrict__ bxf,
    const float* __restrict__ Wxr, const float* __restrict__ bxr,
    float* __restrict__ feat)
{
    __shared__ float sXPc[C*LS];   // xp chunk [c][w]
    __shared__ float sT[C*LS];     // x1/x2 chunk, later score1
    __shared__ float sPT[C*LS];    // xfp/xrp chunk transposed [w][d], later score2

    int t = threadIdx.x;
    int b = blockIdx.x / H, h = blockIdx.x % H;
    const float* xs  = x  + (size_t)b*C*HW + (size_t)h*WD;
    const float* xfs = xf + (size_t)b*C*HW + (size_t)h*WD;
    const float* xrs = xr + (size_t)b*C*HW + (size_t)h*WD;
    float* f0 = feat + (size_t)b*(2*C)*HW + (size_t)h*WD;

    float sc1[16], sc2[16];
#pragma unroll
    for (int k = 0; k < 16; ++k) { sc1[k] = 0.f; sc2[k] = 0.f; }

    // ---- phase 1: accumulate score1/score2 over two w-chunks ----
    for (int wc = 0; wc < WD; wc += 64) {
        matvecG(Wx, bx, xs + wc, sXPc, t);
        __syncthreads();
        matvecL(Wx1, bx1, sXPc, sT, t);
        matvecGT(Wxf, bxf, xfs + wc, sPT, t);
        __syncthreads();
        score_accum(sT, sPT, sc1, t);
        __syncthreads();
        matvecL(Wx2, bx2, sXPc, sT, t);
        matvecGT(Wxr, bxr, xrs + wc, sPT, t);
        __syncthreads();
        score_accum(sT, sPT, sc2, t);
        __syncthreads();
    }

    // ---- phase 2: scores -> LDS, recompute xp chunk, emit features ----
    store_score(sc1, sT, t);
    store_score(sc2, sPT, t);
    __syncthreads();
    for (int wc = 0; wc < WD; wc += 64) {
        matvecG(Wx, bx, xs + wc, sXPc, t);
        __syncthreads();
        feat_chunk(sT,  sXPc, f0 + wc, t);
        feat_chunk(sPT, sXPc, f0 + (size_t)C*HW + wc, t);
        __syncthreads();
    }
}

// ---------------------------------------------------------------------------
// 3x3 conv 192->192 + bias + BN(eval) + ReLU.
// Block = (b, y, 64-output-channel chunk). 256 threads, each owns 4 o x 8 x.
// Input channels staged 16 at a time (3 rows with halo) in LDS; ch<128 from
// feat buffer, ch>=128 from original x.
// ---------------------------------------------------------------------------
__global__ __launch_bounds__(256) void conv_kernel(
    const float* __restrict__ feat, const float* __restrict__ x,
    const float* __restrict__ Wm,   const float* __restrict__ bias,
    const float* __restrict__ gamma, const float* __restrict__ beta,
    const float* __restrict__ mean,  const float* __restrict__ var,
    float* __restrict__ out)
{
    __shared__ float sIn[16*3*132];   // [i][r][col], col 0..129 = x -1..128
    __shared__ float sW[64*145];      // [o][i*9+tap], odd stride -> conflict-free

    int t  = threadIdx.x;
    int b  = blockIdx.x / H, y = blockIdx.x % H;
    int o0 = blockIdx.y * 64;
    int og = t >> 4;                  // 0..15 -> o = o0 + og*4 + m
    int xb = (t & 15) << 3;           // 0..120

    float acc[4][8];
#pragma unroll
    for (int m = 0; m < 4; ++m)
#pragma unroll
        for (int j = 0; j < 8; ++j) acc[m][j] = 0.f;

    for (int ic0 = 0; ic0 < C3; ic0 += 16) {
        // stage weights: 64 o x 16 i x 9 taps
        for (int k = t; k < 64*144; k += 256) {
            int o = k / 144, rest = k - o*144;
            sW[o*145 + rest] = Wm[(size_t)(o0+o)*C3*9 + (size_t)ic0*9 + rest];
        }
        // stage input: 16 ch x 3 rows x 130 cols (zero-padded halo)
        for (int k = t; k < 16*3*130; k += 256) {
            int col = k % 130;
            int pr  = k / 130;
            int i = pr / 3, r = pr - i*3;
            int gx = col - 1, gy = y + r - 1;
            int ic = ic0 + i;
            float v = 0.f;
            if ((unsigned)gx < 128u && (unsigned)gy < 128u) {
                v = (ic < 2*C) ? feat[((size_t)b*(2*C) + ic)*HW + (size_t)gy*WD + gx]
                               : x[((size_t)b*C + (ic - 2*C))*HW + (size_t)gy*WD + gx];
            }
            sIn[(i*3+r)*132 + col] = v;
        }
        __syncthreads();

        for (int i = 0; i < 16; ++i) {
#pragma unroll
            for (int r = 0; r < 3; ++r) {
                const float* row = sIn + (i*3+r)*132 + xb;
                float rr[10];
                float4 v0 = *(const float4*)(row);
                float4 v1 = *(const float4*)(row + 4);
                rr[0]=v0.x; rr[1]=v0.y; rr[2]=v0.z; rr[3]=v0.w;
                rr[4]=v1.x; rr[5]=v1.y; rr[6]=v1.z; rr[7]=v1.w;
                rr[8]=row[8]; rr[9]=row[9];
#pragma unroll
                for (int m = 0; m < 4; ++m) {
                    const float* wr = sW + (og*4+m)*145 + i*9 + r*3;
#pragma unroll
                    for (int kx = 0; kx < 3; ++kx) {
                        float wv = wr[kx];
#pragma unroll
                        for (int j = 0; j < 8; ++j) acc[m][j] += wv * rr[kx+j];
                    }
                }
            }
        }
        __syncthreads();
    }

    // epilogue: +bias, BN(eval, eps=1e-4), ReLU
#pragma unroll
    for (int m = 0; m < 4; ++m) {
        int o = o0 + og*4 + m;
        float A  = gamma[o] * rsqrtf(var[o] + 1e-4f);
        float Bv = (bias[o] - mean[o]) * A + beta[o];
        float* orow = out + ((size_t)b*C3 + o)*HW + (size_t)y*WD + xb;
        float r0[4], r1[4];
#pragma unroll
        for (int j = 0; j < 4; ++j) r0[j] = fmaxf(acc[m][j]  *A + Bv, 0.f);
#pragma unroll
        for (int j = 0; j < 4; ++j) r1[j] = fmaxf(acc[m][j+4]*A + Bv, 0.f);
        *(float4*)(orow)     = make_float4(r0[0], r0[1], r0[2], r0[3]);
        *(float4*)(orow + 4) = make_float4(r1[0], r1[1], r1[2], r1[3]);
    }
}

extern "C" void kernel_launch(void* const* d_in, const int* in_sizes, int n_in,
                              void* d_out, int out_size, void* d_ws, size_t ws_size,
                              hipStream_t stream)
{
    const float* x   = (const float*)d_in[0];
    const float* xf  = (const float*)d_in[1];
    const float* xr  = (const float*)d_in[2];
    const float* Wx  = (const float*)d_in[3];
    const float* bx  = (const float*)d_in[4];
    const float* Wx1 = (const float*)d_in[5];
    const float* bx1 = (const float*)d_in[6];
    const float* Wx2 = (const float*)d_in[7];
    const float* bx2 = (const float*)d_in[8];
    const float* Wxf = (const float*)d_in[9];
    const float* bxf = (const float*)d_in[10];
    const float* Wxr = (const float*)d_in[11];
    const float* bxr = (const float*)d_in[12];
    const float* Wm  = (const float*)d_in[13];
    const float* bms = (const float*)d_in[14];
    const float* gam = (const float*)d_in[15];
    const float* bet = (const float*)d_in[16];
    const float* mea = (const float*)d_in[17];
    const float* va  = (const float*)d_in[18];
    (void)in_sizes; (void)n_in; (void)out_size; (void)ws_size;

    float* feat = (float*)d_ws;          // (B, 128, H, W) f32 = 67.1 MB
    float* outp = (float*)d_out;

    attn_kernel<<<dim3(BATCH*H), dim3(256), 0, stream>>>(
        x, xf, xr, Wx, bx, Wx1, bx1, Wx2, bx2, Wxf, bxf, Wxr, bxr, feat);
    conv_kernel<<<dim3(BATCH*H, 3), dim3(256), 0, stream>>>(
        feat, x, Wm, bms, gam, bet, mea, va, outp);
}

// Round 2
// 1210.507 us; speedup vs baseline: 2.3243x; 2.3243x over previous
//
#include <hip/hip_runtime.h>

#define BATCH 8
#define C     64
#define H     128
#define WD    128
#define C3    192
#define HW    (H*WD)
#define LS    68          // LDS row stride for 64x64 f32 chunk tiles
#define PW    130         // padded H/W for conv input
#define ICS   192         // channel count / stride in inT2 (channel-last)

typedef __attribute__((ext_vector_type(8))) short short8;
typedef __attribute__((ext_vector_type(4))) float f32x4;
typedef unsigned short ushort_t;

__device__ __forceinline__ unsigned short f2bf(float f) {
    unsigned u = __builtin_bit_cast(unsigned, f);
    u += 0x7fffu + ((u >> 16) & 1u);
    return (unsigned short)(u >> 16);
}

// ===========================================================================
// Attention kernel (fp32, unchanged math): one block per (b,h). 256 threads.
// Phase 2 now writes features as bf16 channel-last directly into inT2
// (padded (B,130,130,192)): c 0..63 = feature_xf, 64..127 = feature_xr.
// ===========================================================================

__device__ __forceinline__ void matvecG(const float* __restrict__ Wm, const float* __restrict__ bias,
                                        const float* __restrict__ gsrc, float* __restrict__ dst, int t)
{
    int o = t >> 2;
    int q = (t & 3) << 2;
    float bv = bias[o];
    float acc[4][4];
#pragma unroll
    for (int k = 0; k < 4; ++k) { acc[k][0]=bv; acc[k][1]=bv; acc[k][2]=bv; acc[k][3]=bv; }
    const float* wrow = Wm + o*C;
    for (int c = 0; c < C; ++c) {
        float wgt = wrow[c];
        const float* row = gsrc + (size_t)c*HW + q;
#pragma unroll
        for (int k = 0; k < 4; ++k) {
            float4 v = *(const float4*)(row + 16*k);
            acc[k][0] += wgt*v.x; acc[k][1] += wgt*v.y; acc[k][2] += wgt*v.z; acc[k][3] += wgt*v.w;
        }
    }
#pragma unroll
    for (int k = 0; k < 4; ++k)
        *(float4*)(dst + o*LS + q + 16*k) = make_float4(acc[k][0],acc[k][1],acc[k][2],acc[k][3]);
}

__device__ __forceinline__ void matvecGT(const float* __restrict__ Wm, const float* __restrict__ bias,
                                         const float* __restrict__ gsrc, float* __restrict__ dstT, int t)
{
    int o = t >> 2;
    int q = (t & 3) << 2;
    float bv = bias[o];
    float acc[4][4];
#pragma unroll
    for (int k = 0; k < 4; ++k) { acc[k][0]=bv; acc[k][1]=bv; acc[k][2]=bv; acc[k][3]=bv; }
    const float* wrow = Wm + o*C;
    for (int c = 0; c < C; ++c) {
        float wgt = wrow[c];
        const float* row = gsrc + (size_t)c*HW + q;
#pragma unroll
        for (int k = 0; k < 4; ++k) {
            float4 v = *(const float4*)(row + 16*k);
            acc[k][0] += wgt*v.x; acc[k][1] += wgt*v.y; acc[k][2] += wgt*v.z; acc[k][3] += wgt*v.w;
        }
    }
#pragma unroll
    for (int k = 0; k < 4; ++k) {
        int wb = q + 16*k;
        dstT[(wb+0)*LS + o] = acc[k][0];
        dstT[(wb+1)*LS + o] = acc[k][1];
        dstT[(wb+2)*LS + o] = acc[k][2];
        dstT[(wb+3)*LS + o] = acc[k][3];
    }
}

__device__ __forceinline__ void matvecL(const float* __restrict__ Wm, const float* __restrict__ bias,
                                        const float* __restrict__ src, float* __restrict__ dst, int t)
{
    int o = t >> 2;
    int q = (t & 3) << 2;
    float bv = bias[o];
    float acc[4][4];
#pragma unroll
    for (int k = 0; k < 4; ++k) { acc[k][0]=bv; acc[k][1]=bv; acc[k][2]=bv; acc[k][3]=bv; }
    const float* wrow = Wm + o*C;
    for (int c = 0; c < C; ++c) {
        float wgt = wrow[c];
        const float* row = src + c*LS + q;
#pragma unroll
        for (int k = 0; k < 4; ++k) {
            float4 v = *(const float4*)(row + 16*k);
            acc[k][0] += wgt*v.x; acc[k][1] += wgt*v.y; acc[k][2] += wgt*v.z; acc[k][3] += wgt*v.w;
        }
    }
#pragma unroll
    for (int k = 0; k < 4; ++k)
        *(float4*)(dst + o*LS + q + 16*k) = make_float4(acc[k][0],acc[k][1],acc[k][2],acc[k][3]);
}

__device__ __forceinline__ void score_accum(const float* __restrict__ sA, const float* __restrict__ sBT,
                                            float* __restrict__ acc, int t)
{
    int c0 = (t >> 4) << 2;
    int d0 = (t & 15) << 2;
    for (int w4 = 0; w4 < 16; ++w4) {
        int w = w4 << 2;
        float4 a[4];
#pragma unroll
        for (int i = 0; i < 4; ++i) a[i] = *(const float4*)(sA + (c0+i)*LS + w);
#pragma unroll
        for (int dw = 0; dw < 4; ++dw) {
            float4 bb = *(const float4*)(sBT + (w+dw)*LS + d0);
#pragma unroll
            for (int i = 0; i < 4; ++i) {
                float av = (dw==0)?a[i].x:(dw==1)?a[i].y:(dw==2)?a[i].z:a[i].w;
                acc[i*4+0] += av*bb.x; acc[i*4+1] += av*bb.y;
                acc[i*4+2] += av*bb.z; acc[i*4+3] += av*bb.w;
            }
        }
    }
}

__device__ __forceinline__ void store_score(const float* __restrict__ acc, float* __restrict__ sS, int t)
{
    int c0 = (t >> 4) << 2;
    int d0 = (t & 15) << 2;
#pragma unroll
    for (int i = 0; i < 4; ++i)
        *(float4*)(sS + (c0+i)*LS + d0) = make_float4(acc[i*4+0],acc[i*4+1],acc[i*4+2],acc[i*4+3]);
}

// feature chunk into registers: out[o][w] = sum_d score[o][d] * xp[d][w]
__device__ __forceinline__ void feat_regs(const float* __restrict__ sS, const float* __restrict__ sXPc,
                                          float* __restrict__ acc, int t)
{
    int o = t >> 2;
    int q = (t & 3) << 2;
#pragma unroll
    for (int k = 0; k < 16; ++k) acc[k] = 0.f;
    for (int d = 0; d < C; ++d) {
        float s = sS[o*LS + d];
        const float* row = sXPc + d*LS + q;
#pragma unroll
        for (int k = 0; k < 4; ++k) {
            float4 v = *(const float4*)(row + 16*k);
            acc[k*4+0] += s*v.x; acc[k*4+1] += s*v.y; acc[k*4+2] += s*v.z; acc[k*4+3] += s*v.w;
        }
    }
}

__global__ __launch_bounds__(256) void attn_kernel(
    const float* __restrict__ x,  const float* __restrict__ xf, const float* __restrict__ xr,
    const float* __restrict__ Wx,  const float* __restrict__ bx,
    const float* __restrict__ Wx1, const float* __restrict__ bx1,
    const float* __restrict__ Wx2, const float* __restrict__ bx2,
    const float* __restrict__ Wxf, const float* __restrict__ bxf,
    const float* __restrict__ Wxr, const float* __restrict__ bxr,
    ushort_t* __restrict__ inT2)
{
    __shared__ float sXPc[C*LS];   // xp chunk [c][w]; phase-2: reused as bf16 [w][136]
    __shared__ float sT[C*LS];     // x1/x2 chunk, later score1
    __shared__ float sPT[C*LS];    // xfp/xrp transposed, later score2

    int t = threadIdx.x;
    int b = blockIdx.x / H, h = blockIdx.x % H;
    const float* xs  = x  + (size_t)b*C*HW + (size_t)h*WD;
    const float* xfs = xf + (size_t)b*C*HW + (size_t)h*WD;
    const float* xrs = xr + (size_t)b*C*HW + (size_t)h*WD;

    float sc1[16], sc2[16];
#pragma unroll
    for (int k = 0; k < 16; ++k) { sc1[k] = 0.f; sc2[k] = 0.f; }

    // ---- phase 1: accumulate score1/score2 over two w-chunks ----
    for (int wc = 0; wc < WD; wc += 64) {
        matvecG(Wx, bx, xs + wc, sXPc, t);
        __syncthreads();
        matvecL(Wx1, bx1, sXPc, sT, t);
        matvecGT(Wxf, bxf, xfs + wc, sPT, t);
        __syncthreads();
        score_accum(sT, sPT, sc1, t);
        __syncthreads();
        matvecL(Wx2, bx2, sXPc, sT, t);
        matvecGT(Wxr, bxr, xrs + wc, sPT, t);
        __syncthreads();
        score_accum(sT, sPT, sc2, t);
        __syncthreads();
    }

    // ---- phase 2: scores -> LDS, recompute xp chunk, emit bf16 features ----
    store_score(sc1, sT, t);
    store_score(sc2, sPT, t);
    __syncthreads();
    for (int wc = 0; wc < WD; wc += 64) {
        matvecG(Wx, bx, xs + wc, sXPc, t);
        __syncthreads();
        float f1[16], f2[16];
        feat_regs(sT,  sXPc, f1, t);
        feat_regs(sPT, sXPc, f2, t);
        __syncthreads();                       // done reading sXPc
        // transpose to bf16 [w][c] in reused sXPc (stride 136 shorts, 16B-aligned rows)
        ushort_t* so = (ushort_t*)sXPc;
        {
            int o = t >> 2, q = (t & 3) << 2;
#pragma unroll
            for (int k = 0; k < 4; ++k)
#pragma unroll
                for (int cp = 0; cp < 4; ++cp) {
                    int w = q + 16*k + cp;
                    so[w*136 + o]      = f2bf(f1[k*4+cp]);
                    so[w*136 + 64 + o] = f2bf(f2[k*4+cp]);
                }
        }
        __syncthreads();
        // cooperative write: 64 w-rows x 128 c bf16 (256B contiguous per row)
        ushort_t* rowbase = inT2 + (((size_t)b*PW + (h+1))*PW + (wc + 1))*ICS;
#pragma unroll
        for (int i = 0; i < 4; ++i) {
            int j = i*256 + t;
            int ww = j >> 4, seg = j & 15;
            *(int4*)(rowbase + (size_t)ww*ICS + seg*8) = *(const int4*)(so + ww*136 + seg*8);
        }
        __syncthreads();                       // before next wc overwrites sXPc
    }
}

// ===========================================================================
// prep kernel: x -> inT2[...][128..191] bf16 (channel-last) + zero all halos.
// grid (B*130) blocks x 256.
// ===========================================================================
__global__ __launch_bounds__(256) void prep_kernel(const float* __restrict__ x,
                                                   ushort_t* __restrict__ inT2)
{
    int b  = blockIdx.x / PW, py = blockIdx.x % PW;
    int t  = threadIdx.x;
    ushort_t* rowp = inT2 + ((size_t)b*PW + py)*(size_t)PW*ICS;

    if (py == 0 || py == PW-1) {
        // zero full padded row: 130*192 shorts = 1560 int4
        int4 z = make_int4(0,0,0,0);
        for (int j = t; j < PW*ICS/8; j += 256) ((int4*)rowp)[j] = z;
        return;
    }
    // zero halo cols 0 and 129 (all 192 c): 2 * 24 int4
    if (t < 48) {
        int side = t / 24, seg = t % 24;
        ((int4*)(rowp + (size_t)(side ? (PW-1) : 0)*ICS))[seg] = make_int4(0,0,0,0);
    }
    // transpose x[b][c][y][:] (c 0..63) -> rowp[x+1][128+c] bf16
    __shared__ ushort_t sx[128*72];
    int y = py - 1;
    for (int k = t; k < 64*128; k += 256) {
        int c = k >> 7, xx = k & 127;
        sx[xx*72 + c] = f2bf(x[((size_t)b*C + c)*HW + (size_t)y*WD + xx]);
    }
    __syncthreads();
    for (int j = t; j < 128*8; j += 256) {
        int xx = j >> 3, seg = j & 7;
        *(int4*)(rowp + (size_t)(xx+1)*ICS + 128 + seg*8) = *(const int4*)(sx + xx*72 + seg*8);
    }
}

// ===========================================================================
// weight pack: W_msa (192,192,3,3) f32 -> Wpack[otile][tap*6+icc][lane][8] bf16
// exact B-fragment order for mfma_f32_16x16x32_bf16.
// ===========================================================================
__global__ __launch_bounds__(256) void pack_kernel(const float* __restrict__ W,
                                                   ushort_t* __restrict__ Wpk)
{
    int k = blockIdx.x*256 + threadIdx.x;       // 12*54*64 = 41472 lanes
    if (k >= 12*54*64) return;
    int lane = k & 63, os = k >> 6;
    int otile = os / 54, s = os % 54;
    int tap = s / 6, icc = s % 6;
    int o   = otile*16 + (lane & 15);
    int ic0 = icc*32 + (lane >> 4)*8;
    ushort_t v[8];
#pragma unroll
    for (int j = 0; j < 8; ++j)
        v[j] = f2bf(W[(size_t)(o*C3 + ic0 + j)*9 + tap]);
    *(int4*)(Wpk + (size_t)k*8) = *(const int4*)v;
}

// ===========================================================================
// conv: implicit-GEMM bf16 MFMA. Block = (b, y-pair, 64-o chunk), 256 threads
// = 4 waves (oi = wave>>1 picks 32-o half, xi = wave&1 picks row).
// Per icc chunk: stage [4 rows][130 gx][32 c] bf16 via global_load_lds(16B),
// then 9 taps x 8 x-subtiles x 2 o-tiles of mfma_f32_16x16x32_bf16.
// ===========================================================================
__global__ __launch_bounds__(256) void conv_mfma(
    const ushort_t* __restrict__ inT2, const ushort_t* __restrict__ Wpk,
    const float* __restrict__ bias, const float* __restrict__ gamma,
    const float* __restrict__ beta, const float* __restrict__ mean,
    const float* __restrict__ var,  float* __restrict__ out)
{
    __shared__ ushort_t sIn[4*PW*32];          // 33280 B

    int t = threadIdx.x;
    int wv = t >> 6, lane = t & 63;
    int b  = blockIdx.x >> 6, y0 = (blockIdx.x & 63)*2;
    int o0 = blockIdx.y * 64;
    int oi = wv >> 1, xi = wv & 1;
    int m = lane & 15, quad = lane >> 4;
    int otbase = blockIdx.y*4 + oi*2;

    f32x4 acc[16];
#pragma unroll
    for (int i = 0; i < 16; ++i) acc[i] = (f32x4){0.f,0.f,0.f,0.f};

    for (int icc = 0; icc < 6; ++icc) {
        // ---- stage input chunk: rows y0..y0+3 (padded), cols 0..129, 32 c ----
        for (int i = 0; i < 9; ++i) {
            int sl = i*256 + t;                // 16B slot index, 2080 total
            if (sl < 4*PW*4) {
                int rowgx = sl >> 2, wi = sl & 3;
                int row = rowgx / PW, gx = rowgx - row*PW;
                const ushort_t* g = inT2 + (((size_t)b*PW + y0 + row)*PW + gx)*ICS
                                         + icc*32 + wi*8;
                __builtin_amdgcn_global_load_lds(
                    (const __attribute__((address_space(1))) unsigned int*)g,
                    (__attribute__((address_space(3))) unsigned int*)(sIn + sl*8),
                    16, 0, 0);
            }
        }
        __syncthreads();

#pragma unroll
        for (int tap = 0; tap < 9; ++tap) {
            const int ky = tap / 3, kx = tap % 3;
            const ushort_t* wp = Wpk + (((size_t)otbase*54 + tap*6 + icc)*64 + lane)*8;
            short8 bf0 = *(const short8*)wp;
            short8 bf1 = *(const short8*)(wp + (size_t)54*64*8);
            int rb = ((xi + ky)*PW + kx + m)*32 + quad*8;
#pragma unroll
            for (int xt = 0; xt < 8; ++xt) {
                short8 af = *(const short8*)(sIn + rb + xt*512);
                acc[2*xt]   = __builtin_amdgcn_mfma_f32_16x16x32_bf16(af, bf0, acc[2*xt],   0,0,0);
                acc[2*xt+1] = __builtin_amdgcn_mfma_f32_16x16x32_bf16(af, bf1, acc[2*xt+1], 0,0,0);
            }
        }
        __syncthreads();
    }

    // ---- epilogue: bias + BN(eval, eps=1e-4) + ReLU, fp32 out ----
    int yOut = y0 + xi;
#pragma unroll
    for (int t16 = 0; t16 < 2; ++t16) {
        int o = o0 + oi*32 + t16*16 + m;
        float A  = gamma[o] * rsqrtf(var[o] + 1e-4f);
        float Bv = (bias[o] - mean[o])*A + beta[o];
        float* orow = out + (((size_t)b*C3 + o)*H + yOut)*WD;
#pragma unroll
        for (int xt = 0; xt < 8; ++xt) {
            f32x4 a4 = acc[2*xt + t16];
            float4 v = make_float4(fmaxf(a4[0]*A + Bv, 0.f), fmaxf(a4[1]*A + Bv, 0.f),
                                   fmaxf(a4[2]*A + Bv, 0.f), fmaxf(a4[3]*A + Bv, 0.f));
            *(float4*)(orow + xt*16 + quad*4) = v;
        }
    }
}

extern "C" void kernel_launch(void* const* d_in, const int* in_sizes, int n_in,
                              void* d_out, int out_size, void* d_ws, size_t ws_size,
                              hipStream_t stream)
{
    const float* x   = (const float*)d_in[0];
    const float* xf  = (const float*)d_in[1];
    const float* xr  = (const float*)d_in[2];
    const float* Wx  = (const float*)d_in[3];
    const float* bx  = (const float*)d_in[4];
    const float* Wx1 = (const float*)d_in[5];
    const float* bx1 = (const float*)d_in[6];
    const float* Wx2 = (const float*)d_in[7];
    const float* bx2 = (const float*)d_in[8];
    const float* Wxf = (const float*)d_in[9];
    const float* bxf = (const float*)d_in[10];
    const float* Wxr = (const float*)d_in[11];
    const float* bxr = (const float*)d_in[12];
    const float* Wm  = (const float*)d_in[13];
    const float* bms = (const float*)d_in[14];
    const float* gam = (const float*)d_in[15];
    const float* bet = (const float*)d_in[16];
    const float* mea = (const float*)d_in[17];
    const float* va  = (const float*)d_in[18];
    (void)in_sizes; (void)n_in; (void)out_size; (void)ws_size;

    // ws layout: inT2 (B,130,130,192) bf16 = 51,916,800 B ; Wpack at +52,000,000
    ushort_t* inT2 = (ushort_t*)d_ws;
    ushort_t* Wpk  = (ushort_t*)((char*)d_ws + 52000000);
    float* outp = (float*)d_out;

    pack_kernel<<<dim3(162), dim3(256), 0, stream>>>(Wm, Wpk);
    prep_kernel<<<dim3(BATCH*PW), dim3(256), 0, stream>>>(x, inT2);
    attn_kernel<<<dim3(BATCH*H), dim3(256), 0, stream>>>(
        x, xf, xr, Wx, bx, Wx1, bx1, Wx2, bx2, Wxf, bxf, Wxr, bxr, inT2);
    conv_mfma<<<dim3(BATCH*(H/2), 3), dim3(256), 0, stream>>>(
        inT2, Wpk, bms, gam, bet, mea, va, outp);
}

// Round 3
// 511.998 us; speedup vs baseline: 5.4952x; 2.3643x over previous
//
#include <hip/hip_runtime.h>

#define BATCH 8
#define C     64
#define H     128
#define WD    128
#define C3    192
#define HW    (H*WD)
#define PW    130         // padded H/W for conv input
#define ICS   192         // channel stride in inT2 (channel-last)
#define STR   72          // LDS row stride in shorts (16B-aligned rows, even bank spread)

typedef __attribute__((ext_vector_type(8))) short short8;
typedef __attribute__((ext_vector_type(4))) float f32x4;
typedef unsigned short ushort_t;

__device__ __forceinline__ unsigned short f2bf(float f) {
    unsigned u = __builtin_bit_cast(unsigned, f);
    u += 0x7fffu + ((u >> 16) & 1u);
    return (unsigned short)(u >> 16);
}
__device__ __forceinline__ int pack2(unsigned short lo, unsigned short hi) {
    return (int)(((unsigned)hi << 16) | (unsigned)lo);
}

// ===========================================================================
// compose_kernel: Wx1c = Wx1@Wx, bx1c = Wx1@bx+bx1 (same for x2); pack all 5
// weight mats to bf16 [o][c] row-major (A/B-frag friendly) + f32 biases.
// Wall: [5][64][64] bf16 (0=Wx,1=Wx1c,2=Wx2c,3=Wxf,4=Wxr); ball: [5][64] f32.
// ===========================================================================
__global__ __launch_bounds__(256) void compose_kernel(
    const float* __restrict__ Wx,  const float* __restrict__ bx,
    const float* __restrict__ Wx1, const float* __restrict__ bx1,
    const float* __restrict__ Wx2, const float* __restrict__ bx2,
    const float* __restrict__ Wxf, const float* __restrict__ bxf,
    const float* __restrict__ Wxr, const float* __restrict__ bxr,
    ushort_t* __restrict__ Wall, float* __restrict__ ball)
{
    int t = threadIdx.x;
    int o = t & 63, cq = t >> 6;          // 4 c-ranges of 16
    for (int c = cq*16; c < cq*16 + 16; ++c) {
        Wall[0*4096 + o*64 + c] = f2bf(Wx [o*64 + c]);
        Wall[3*4096 + o*64 + c] = f2bf(Wxf[o*64 + c]);
        Wall[4*4096 + o*64 + c] = f2bf(Wxr[o*64 + c]);
        float a1 = 0.f, a2 = 0.f;
        for (int k = 0; k < 64; ++k) {
            float wc = Wx[k*64 + c];
            a1 += Wx1[o*64 + k] * wc;
            a2 += Wx2[o*64 + k] * wc;
        }
        Wall[1*4096 + o*64 + c] = f2bf(a1);
        Wall[2*4096 + o*64 + c] = f2bf(a2);
    }
    if (cq == 0) {
        ball[0*64 + o] = bx[o];
        ball[3*64 + o] = bxf[o];
        ball[4*64 + o] = bxr[o];
        float b1 = bx1[o], b2 = bx2[o];
        for (int k = 0; k < 64; ++k) {
            b1 += Wx1[o*64 + k] * bx[k];
            b2 += Wx2[o*64 + k] * bx[k];
        }
        ball[1*64 + o] = b1;
        ball[2*64 + o] = b2;
    }
}

// ===========================================================================
// attn_mfma: one block per (b,h), 256 threads = 4 waves. All GEMMs via
// mfma_f32_16x16x32_bf16. LDS: 4 buffers [64][STR] bf16 = 36.9 KB -> 4 blk/CU.
// Phase 1 (per w-chunk of 64): stage X^T, x1=W1c@X, xf^T, xfp, score1 += x1.xfp^T
// (regs), X^r, xrp, x2, score2. Phase 2: scores->bf16 A-layout, per chunk
// recompute xp^T, features = score@xp -> bf16 channel-last into inT2.
// ===========================================================================
__global__ __launch_bounds__(256, 4) void attn_mfma(
    const float* __restrict__ x, const float* __restrict__ xf, const float* __restrict__ xr,
    const ushort_t* __restrict__ Wall, const float* __restrict__ ball,
    ushort_t* __restrict__ inT2)
{
    __shared__ ushort_t lds[4*64*STR];
    ushort_t* P = lds;                 // XT staging / score1bf
    ushort_t* Q = lds + 64*STR;        // Xf/Xr staging / phase2 XT + feature staging
    ushort_t* R = lds + 2*64*STR;      // x1 / x2 / score2bf
    ushort_t* T = lds + 3*64*STR;      // xfp / xrp / xpT chunk

    const int t = threadIdx.x;
    const int wv = t >> 6, lane = t & 63, m = lane & 15, quad = lane >> 4;
    const int b = blockIdx.x >> 7, h = blockIdx.x & 127;
    const float* xs  = x  + (size_t)b*C*HW + (size_t)h*WD;
    const float* xfs = xf + (size_t)b*C*HW + (size_t)h*WD;
    const float* xrs = xr + (size_t)b*C*HW + (size_t)h*WD;

    // ---- helpers (inlined lambdas) ----
    // stage: global f32 [c][w-chunk] -> LDS bf16 transposed [w][c], stride STR
    auto stage = [&](const float* src, int wc, ushort_t* dst) {
        int c = t >> 2, wq = (t & 3) << 4;
        const float* p = src + (size_t)c*HW + wc + wq;
        float4 v0 = *(const float4*)(p);
        float4 v1 = *(const float4*)(p + 4);
        float4 v2 = *(const float4*)(p + 8);
        float4 v3 = *(const float4*)(p + 12);
        float vv[16] = {v0.x,v0.y,v0.z,v0.w, v1.x,v1.y,v1.z,v1.w,
                        v2.x,v2.y,v2.z,v2.w, v3.x,v3.y,v3.z,v3.w};
#pragma unroll
        for (int j = 0; j < 16; ++j) dst[(wq + j)*STR + c] = f2bf(vv[j]);
    };
    // projB: out[o][w] = sum_c W[o][c]*src^T[w][c] + bias  (A=srcT rows, B=W rows)
    auto projB = [&](const ushort_t* src, const ushort_t* W, const float* bias,
                     ushort_t* dst) {
        int mt = wv;  // w-tile
#pragma unroll
        for (int nt = 0; nt < 4; ++nt) {
            f32x4 acc = {0.f,0.f,0.f,0.f};
#pragma unroll
            for (int k = 0; k < 2; ++k) {
                short8 a  = *(const short8*)(src + (mt*16 + m)*STR + k*32 + quad*8);
                short8 bb = *(const short8*)(W   + (nt*16 + m)*64  + k*32 + quad*8);
                acc = __builtin_amdgcn_mfma_f32_16x16x32_bf16(a, bb, acc, 0,0,0);
            }
            float bo = bias[nt*16 + m];
            int o = nt*16 + m, w0 = mt*16 + quad*4;
            *(int*)(dst + o*STR + w0)     = pack2(f2bf(acc[0]+bo), f2bf(acc[1]+bo));
            *(int*)(dst + o*STR + w0 + 2) = pack2(f2bf(acc[2]+bo), f2bf(acc[3]+bo));
        }
    };
    // projA: xpT[w][o] = sum_c W[o][c]*srcT[w][c] + bias  (A=W rows, B=srcT rows)
    auto projA = [&](const ushort_t* src, const ushort_t* W, const float* bias,
                     ushort_t* dstT) {
        int mt = wv;  // o-tile
        float b4[4];
#pragma unroll
        for (int r = 0; r < 4; ++r) b4[r] = bias[mt*16 + quad*4 + r];
#pragma unroll
        for (int nt = 0; nt < 4; ++nt) {
            f32x4 acc = {0.f,0.f,0.f,0.f};
#pragma unroll
            for (int k = 0; k < 2; ++k) {
                short8 a  = *(const short8*)(W   + (mt*16 + m)*64  + k*32 + quad*8);
                short8 bb = *(const short8*)(src + (nt*16 + m)*STR + k*32 + quad*8);
                acc = __builtin_amdgcn_mfma_f32_16x16x32_bf16(a, bb, acc, 0,0,0);
            }
            int w = nt*16 + m, o0 = mt*16 + quad*4;
            *(int*)(dstT + w*STR + o0)     = pack2(f2bf(acc[0]+b4[0]), f2bf(acc[1]+b4[1]));
            *(int*)(dstT + w*STR + o0 + 2) = pack2(f2bf(acc[2]+b4[2]), f2bf(acc[3]+b4[3]));
        }
    };
    // score: sc[nt] += A[c][w-chunk] . B^T (both [row][w] layouts)
    auto scoreStep = [&](const ushort_t* A, const ushort_t* B, f32x4* sc) {
        int mt = wv;
#pragma unroll
        for (int nt = 0; nt < 4; ++nt)
#pragma unroll
            for (int k = 0; k < 2; ++k) {
                short8 a  = *(const short8*)(A + (mt*16 + m)*STR + k*32 + quad*8);
                short8 bb = *(const short8*)(B + (nt*16 + m)*STR + k*32 + quad*8);
                sc[nt] = __builtin_amdgcn_mfma_f32_16x16x32_bf16(a, bb, sc[nt], 0,0,0);
            }
    };
    auto scoreDump = [&](const f32x4* sc, ushort_t* dst) {
        int c0 = wv*16 + quad*4;
#pragma unroll
        for (int nt = 0; nt < 4; ++nt) {
            int d = nt*16 + m;
#pragma unroll
            for (int r = 0; r < 4; ++r) dst[(c0 + r)*STR + d] = f2bf(sc[nt][r]);
        }
    };
    // feature: stg[w][c] = sum_d scorebf[c][d]*xpT[w][d]
    auto feat = [&](const ushort_t* Sc, const ushort_t* XpT, ushort_t* stg) {
        int mt = wv;  // c-tile
#pragma unroll
        for (int nt = 0; nt < 4; ++nt) {
            f32x4 acc = {0.f,0.f,0.f,0.f};
#pragma unroll
            for (int k = 0; k < 2; ++k) {
                short8 a  = *(const short8*)(Sc  + (mt*16 + m)*STR + k*32 + quad*8);
                short8 bb = *(const short8*)(XpT + (nt*16 + m)*STR + k*32 + quad*8);
                acc = __builtin_amdgcn_mfma_f32_16x16x32_bf16(a, bb, acc, 0,0,0);
            }
            int w = nt*16 + m, c0 = mt*16 + quad*4;
            *(int*)(stg + w*STR + c0)     = pack2(f2bf(acc[0]), f2bf(acc[1]));
            *(int*)(stg + w*STR + c0 + 2) = pack2(f2bf(acc[2]), f2bf(acc[3]));
        }
    };
    // emit one branch: staging [64 w][64 c] bf16 -> inT2 rows at channel coff
    auto emitBr = [&](const ushort_t* stg, int wc, int coff) {
#pragma unroll
        for (int it = 0; it < 2; ++it) {
            int j = it*256 + t;
            int row = j >> 3, seg = j & 7;
            int v[4];
#pragma unroll
            for (int k = 0; k < 4; ++k) v[k] = *(const int*)(stg + row*STR + seg*8 + k*2);
            ushort_t* dst = inT2 + (((size_t)b*PW + h + 1)*PW + (wc + 1 + row))*ICS
                                 + coff + seg*8;
            *(int4*)dst = make_int4(v[0], v[1], v[2], v[3]);
        }
    };

    const ushort_t* W0 = Wall;            const float* b0 = ball;
    const ushort_t* W1 = Wall + 4096;     const float* b1 = ball + 64;
    const ushort_t* W2 = Wall + 2*4096;   const float* b2 = ball + 128;
    const ushort_t* W3 = Wall + 3*4096;   const float* b3 = ball + 192;
    const ushort_t* W4 = Wall + 4*4096;   const float* b4 = ball + 256;

    f32x4 sc1[4], sc2[4];
#pragma unroll
    for (int i = 0; i < 4; ++i) { sc1[i] = (f32x4){0,0,0,0}; sc2[i] = (f32x4){0,0,0,0}; }

    // ---- phase 1: scores ----
    for (int wc = 0; wc < WD; wc += 64) {
        stage(xs, wc, P);            __syncthreads();
        projB(P, W1, b1, R);         stage(xfs, wc, Q);   __syncthreads();  // x1
        projB(Q, W3, b3, T);         __syncthreads();                       // xfp
        scoreStep(R, T, sc1);        stage(xrs, wc, Q);   __syncthreads();
        projB(P, W2, b2, R);         projB(Q, W4, b4, T); __syncthreads();  // x2, xrp
        scoreStep(R, T, sc2);        __syncthreads();
    }

    // ---- phase 2: features ----
    scoreDump(sc1, P);  scoreDump(sc2, R);  __syncthreads();
    for (int wc = 0; wc < WD; wc += 64) {
        stage(xs, wc, Q);            __syncthreads();
        projA(Q, W0, b0, T);         __syncthreads();     // xpT chunk
        feat(P, T, Q);               __syncthreads();     // branch f (Q's XT dead)
        emitBr(Q, wc, 0);            __syncthreads();
        feat(R, T, Q);               __syncthreads();     // branch r
        emitBr(Q, wc, 64);           __syncthreads();
    }
}

// ===========================================================================
// prep kernel: x -> inT2[...][128..191] bf16 (channel-last) + zero all halos.
// ===========================================================================
__global__ __launch_bounds__(256) void prep_kernel(const float* __restrict__ x,
                                                   ushort_t* __restrict__ inT2)
{
    int b  = blockIdx.x / PW, py = blockIdx.x % PW;
    int t  = threadIdx.x;
    ushort_t* rowp = inT2 + ((size_t)b*PW + py)*(size_t)PW*ICS;

    if (py == 0 || py == PW-1) {
        int4 z = make_int4(0,0,0,0);
        for (int j = t; j < PW*ICS/8; j += 256) ((int4*)rowp)[j] = z;
        return;
    }
    if (t < 48) {
        int side = t / 24, seg = t % 24;
        ((int4*)(rowp + (size_t)(side ? (PW-1) : 0)*ICS))[seg] = make_int4(0,0,0,0);
    }
    __shared__ ushort_t sx[128*72];
    int y = py - 1;
    for (int k = t; k < 64*128; k += 256) {
        int c = k >> 7, xx = k & 127;
        sx[xx*72 + c] = f2bf(x[((size_t)b*C + c)*HW + (size_t)y*WD + xx]);
    }
    __syncthreads();
    for (int j = t; j < 128*8; j += 256) {
        int xx = j >> 3, seg = j & 7;
        *(int4*)(rowp + (size_t)(xx+1)*ICS + 128 + seg*8) = *(const int4*)(sx + xx*72 + seg*8);
    }
}

// ===========================================================================
// weight pack for conv: W_msa -> Wpack[otile][tap*6+icc][lane][8] bf16.
// ===========================================================================
__global__ __launch_bounds__(256) void pack_kernel(const float* __restrict__ W,
                                                   ushort_t* __restrict__ Wpk)
{
    int k = blockIdx.x*256 + threadIdx.x;
    if (k >= 12*54*64) return;
    int lane = k & 63, os = k >> 6;
    int otile = os / 54, s = os % 54;
    int tap = s / 6, icc = s % 6;
    int o   = otile*16 + (lane & 15);
    int ic0 = icc*32 + (lane >> 4)*8;
    ushort_t v[8];
#pragma unroll
    for (int j = 0; j < 8; ++j)
        v[j] = f2bf(W[(size_t)(o*C3 + ic0 + j)*9 + tap]);
    *(int4*)(Wpk + (size_t)k*8) = *(const int4*)v;
}

// ===========================================================================
// conv: implicit-GEMM bf16 MFMA (unchanged from R2).
// ===========================================================================
__global__ __launch_bounds__(256) void conv_mfma(
    const ushort_t* __restrict__ inT2, const ushort_t* __restrict__ Wpk,
    const float* __restrict__ bias, const float* __restrict__ gamma,
    const float* __restrict__ beta, const float* __restrict__ mean,
    const float* __restrict__ var,  float* __restrict__ out)
{
    __shared__ ushort_t sIn[4*PW*32];

    int t = threadIdx.x;
    int wv = t >> 6, lane = t & 63;
    int b  = blockIdx.x >> 6, y0 = (blockIdx.x & 63)*2;
    int o0 = blockIdx.y * 64;
    int oi = wv >> 1, xi = wv & 1;
    int m = lane & 15, quad = lane >> 4;
    int otbase = blockIdx.y*4 + oi*2;

    f32x4 acc[16];
#pragma unroll
    for (int i = 0; i < 16; ++i) acc[i] = (f32x4){0.f,0.f,0.f,0.f};

    for (int icc = 0; icc < 6; ++icc) {
        for (int i = 0; i < 9; ++i) {
            int sl = i*256 + t;
            if (sl < 4*PW*4) {
                int rowgx = sl >> 2, wi = sl & 3;
                int row = rowgx / PW, gx = rowgx - row*PW;
                const ushort_t* g = inT2 + (((size_t)b*PW + y0 + row)*PW + gx)*ICS
                                         + icc*32 + wi*8;
                __builtin_amdgcn_global_load_lds(
                    (const __attribute__((address_space(1))) unsigned int*)g,
                    (__attribute__((address_space(3))) unsigned int*)(sIn + sl*8),
                    16, 0, 0);
            }
        }
        __syncthreads();

#pragma unroll
        for (int tap = 0; tap < 9; ++tap) {
            const int ky = tap / 3, kx = tap % 3;
            const ushort_t* wp = Wpk + (((size_t)otbase*54 + tap*6 + icc)*64 + lane)*8;
            short8 bf0 = *(const short8*)wp;
            short8 bf1 = *(const short8*)(wp + (size_t)54*64*8);
            int rb = ((xi + ky)*PW + kx + m)*32 + quad*8;
#pragma unroll
            for (int xt = 0; xt < 8; ++xt) {
                short8 af = *(const short8*)(sIn + rb + xt*512);
                acc[2*xt]   = __builtin_amdgcn_mfma_f32_16x16x32_bf16(af, bf0, acc[2*xt],   0,0,0);
                acc[2*xt+1] = __builtin_amdgcn_mfma_f32_16x16x32_bf16(af, bf1, acc[2*xt+1], 0,0,0);
            }
        }
        __syncthreads();
    }

    int yOut = y0 + xi;
#pragma unroll
    for (int t16 = 0; t16 < 2; ++t16) {
        int o = o0 + oi*32 + t16*16 + m;
        float A  = gamma[o] * rsqrtf(var[o] + 1e-4f);
        float Bv = (bias[o] - mean[o])*A + beta[o];
        float* orow = out + (((size_t)b*C3 + o)*H + yOut)*WD;
#pragma unroll
        for (int xt = 0; xt < 8; ++xt) {
            f32x4 a4 = acc[2*xt + t16];
            float4 v = make_float4(fmaxf(a4[0]*A + Bv, 0.f), fmaxf(a4[1]*A + Bv, 0.f),
                                   fmaxf(a4[2]*A + Bv, 0.f), fmaxf(a4[3]*A + Bv, 0.f));
            *(float4*)(orow + xt*16 + quad*4) = v;
        }
    }
}

extern "C" void kernel_launch(void* const* d_in, const int* in_sizes, int n_in,
                              void* d_out, int out_size, void* d_ws, size_t ws_size,
                              hipStream_t stream)
{
    const float* x   = (const float*)d_in[0];
    const float* xf  = (const float*)d_in[1];
    const float* xr  = (const float*)d_in[2];
    const float* Wx  = (const float*)d_in[3];
    const float* bx  = (const float*)d_in[4];
    const float* Wx1 = (const float*)d_in[5];
    const float* bx1 = (const float*)d_in[6];
    const float* Wx2 = (const float*)d_in[7];
    const float* bx2 = (const float*)d_in[8];
    const float* Wxf = (const float*)d_in[9];
    const float* bxf = (const float*)d_in[10];
    const float* Wxr = (const float*)d_in[11];
    const float* bxr = (const float*)d_in[12];
    const float* Wm  = (const float*)d_in[13];
    const float* bms = (const float*)d_in[14];
    const float* gam = (const float*)d_in[15];
    const float* bet = (const float*)d_in[16];
    const float* mea = (const float*)d_in[17];
    const float* va  = (const float*)d_in[18];
    (void)in_sizes; (void)n_in; (void)out_size; (void)ws_size;

    // ws layout: inT2 (B,130,130,192) bf16 @ 0 (51,916,800 B);
    //            conv Wpack @ 52,000,000 (663,552 B);
    //            attn Wall bf16 @ 52,700,000 (40,960 B); ball f32 @ 52,750,000.
    ushort_t* inT2 = (ushort_t*)d_ws;
    ushort_t* Wpk  = (ushort_t*)((char*)d_ws + 52000000);
    ushort_t* Wall = (ushort_t*)((char*)d_ws + 52700000);
    float*    ball = (float*)   ((char*)d_ws + 52750000);
    float* outp = (float*)d_out;

    compose_kernel<<<dim3(1), dim3(256), 0, stream>>>(
        Wx, bx, Wx1, bx1, Wx2, bx2, Wxf, bxf, Wxr, bxr, Wall, ball);
    pack_kernel<<<dim3(162), dim3(256), 0, stream>>>(Wm, Wpk);
    prep_kernel<<<dim3(BATCH*PW), dim3(256), 0, stream>>>(x, inT2);
    attn_mfma<<<dim3(BATCH*H), dim3(256), 0, stream>>>(
        x, xf, xr, Wall, ball, inT2);
    conv_mfma<<<dim3(BATCH*(H/2), 3), dim3(256), 0, stream>>>(
        inT2, Wpk, bms, gam, bet, mea, va, outp);
}

// Round 4
// 485.220 us; speedup vs baseline: 5.7985x; 1.0552x over previous
//
#include <hip/hip_runtime.h>

#define BATCH 8
#define C     64
#define H     128
#define WD    128
#define C3    192
#define HW    (H*WD)
#define PW    130         // padded H/W for conv input
#define ICS   192         // channel stride in inT2 (channel-last)
#define STR   72          // LDS row stride in shorts (16B-aligned rows, even bank spread)

typedef __attribute__((ext_vector_type(8))) short short8;
typedef __attribute__((ext_vector_type(4))) float f32x4;
typedef unsigned short ushort_t;

__device__ __forceinline__ unsigned short f2bf(float f) {
    unsigned u = __builtin_bit_cast(unsigned, f);
    u += 0x7fffu + ((u >> 16) & 1u);
    return (unsigned short)(u >> 16);
}
__device__ __forceinline__ int pack2(unsigned short lo, unsigned short hi) {
    return (int)(((unsigned)hi << 16) | (unsigned)lo);
}

// ===========================================================================
// compose_kernel: Wx1c = Wx1@Wx, bx1c = Wx1@bx+bx1 (same for x2); pack all 5
// weight mats to bf16 [o][c] row-major + f32 biases.
// Wall: [5][64][64] bf16 (0=Wx,1=Wx1c,2=Wx2c,3=Wxf,4=Wxr); ball: [5][64] f32.
// ===========================================================================
__global__ __launch_bounds__(256) void compose_kernel(
    const float* __restrict__ Wx,  const float* __restrict__ bx,
    const float* __restrict__ Wx1, const float* __restrict__ bx1,
    const float* __restrict__ Wx2, const float* __restrict__ bx2,
    const float* __restrict__ Wxf, const float* __restrict__ bxf,
    const float* __restrict__ Wxr, const float* __restrict__ bxr,
    ushort_t* __restrict__ Wall, float* __restrict__ ball)
{
    int t = threadIdx.x;
    int o = t & 63, cq = t >> 6;
    for (int c = cq*16; c < cq*16 + 16; ++c) {
        Wall[0*4096 + o*64 + c] = f2bf(Wx [o*64 + c]);
        Wall[3*4096 + o*64 + c] = f2bf(Wxf[o*64 + c]);
        Wall[4*4096 + o*64 + c] = f2bf(Wxr[o*64 + c]);
        float a1 = 0.f, a2 = 0.f;
        for (int k = 0; k < 64; ++k) {
            float wc = Wx[k*64 + c];
            a1 += Wx1[o*64 + k] * wc;
            a2 += Wx2[o*64 + k] * wc;
        }
        Wall[1*4096 + o*64 + c] = f2bf(a1);
        Wall[2*4096 + o*64 + c] = f2bf(a2);
    }
    if (cq == 0) {
        ball[0*64 + o] = bx[o];
        ball[3*64 + o] = bxf[o];
        ball[4*64 + o] = bxr[o];
        float b1 = bx1[o], b2 = bx2[o];
        for (int k = 0; k < 64; ++k) {
            b1 += Wx1[o*64 + k] * bx[k];
            b2 += Wx2[o*64 + k] * bx[k];
        }
        ball[1*64 + o] = b1;
        ball[2*64 + o] = b2;
    }
}

// ===========================================================================
// attn_mfma: one block per (b,h), 256 threads = 4 waves (unchanged from R3).
// ===========================================================================
__global__ __launch_bounds__(256, 4) void attn_mfma(
    const float* __restrict__ x, const float* __restrict__ xf, const float* __restrict__ xr,
    const ushort_t* __restrict__ Wall, const float* __restrict__ ball,
    ushort_t* __restrict__ inT2)
{
    __shared__ ushort_t lds[4*64*STR];
    ushort_t* P = lds;
    ushort_t* Q = lds + 64*STR;
    ushort_t* R = lds + 2*64*STR;
    ushort_t* T = lds + 3*64*STR;

    const int t = threadIdx.x;
    const int wv = t >> 6, lane = t & 63, m = lane & 15, quad = lane >> 4;
    const int b = blockIdx.x >> 7, h = blockIdx.x & 127;
    const float* xs  = x  + (size_t)b*C*HW + (size_t)h*WD;
    const float* xfs = xf + (size_t)b*C*HW + (size_t)h*WD;
    const float* xrs = xr + (size_t)b*C*HW + (size_t)h*WD;

    auto stage = [&](const float* src, int wc, ushort_t* dst) {
        int c = t >> 2, wq = (t & 3) << 4;
        const float* p = src + (size_t)c*HW + wc + wq;
        float4 v0 = *(const float4*)(p);
        float4 v1 = *(const float4*)(p + 4);
        float4 v2 = *(const float4*)(p + 8);
        float4 v3 = *(const float4*)(p + 12);
        float vv[16] = {v0.x,v0.y,v0.z,v0.w, v1.x,v1.y,v1.z,v1.w,
                        v2.x,v2.y,v2.z,v2.w, v3.x,v3.y,v3.z,v3.w};
#pragma unroll
        for (int j = 0; j < 16; ++j) dst[(wq + j)*STR + c] = f2bf(vv[j]);
    };
    auto projB = [&](const ushort_t* src, const ushort_t* W, const float* bias,
                     ushort_t* dst) {
        int mt = wv;
#pragma unroll
        for (int nt = 0; nt < 4; ++nt) {
            f32x4 acc = {0.f,0.f,0.f,0.f};
#pragma unroll
            for (int k = 0; k < 2; ++k) {
                short8 a  = *(const short8*)(src + (mt*16 + m)*STR + k*32 + quad*8);
                short8 bb = *(const short8*)(W   + (nt*16 + m)*64  + k*32 + quad*8);
                acc = __builtin_amdgcn_mfma_f32_16x16x32_bf16(a, bb, acc, 0,0,0);
            }
            float bo = bias[nt*16 + m];
            int o = nt*16 + m, w0 = mt*16 + quad*4;
            *(int*)(dst + o*STR + w0)     = pack2(f2bf(acc[0]+bo), f2bf(acc[1]+bo));
            *(int*)(dst + o*STR + w0 + 2) = pack2(f2bf(acc[2]+bo), f2bf(acc[3]+bo));
        }
    };
    auto projA = [&](const ushort_t* src, const ushort_t* W, const float* bias,
                     ushort_t* dstT) {
        int mt = wv;
        float b4[4];
#pragma unroll
        for (int r = 0; r < 4; ++r) b4[r] = bias[mt*16 + quad*4 + r];
#pragma unroll
        for (int nt = 0; nt < 4; ++nt) {
            f32x4 acc = {0.f,0.f,0.f,0.f};
#pragma unroll
            for (int k = 0; k < 2; ++k) {
                short8 a  = *(const short8*)(W   + (mt*16 + m)*64  + k*32 + quad*8);
                short8 bb = *(const short8*)(src + (nt*16 + m)*STR + k*32 + quad*8);
                acc = __builtin_amdgcn_mfma_f32_16x16x32_bf16(a, bb, acc, 0,0,0);
            }
            int w = nt*16 + m, o0 = mt*16 + quad*4;
            *(int*)(dstT + w*STR + o0)     = pack2(f2bf(acc[0]+b4[0]), f2bf(acc[1]+b4[1]));
            *(int*)(dstT + w*STR + o0 + 2) = pack2(f2bf(acc[2]+b4[2]), f2bf(acc[3]+b4[3]));
        }
    };
    auto scoreStep = [&](const ushort_t* A, const ushort_t* B, f32x4* sc) {
        int mt = wv;
#pragma unroll
        for (int nt = 0; nt < 4; ++nt)
#pragma unroll
            for (int k = 0; k < 2; ++k) {
                short8 a  = *(const short8*)(A + (mt*16 + m)*STR + k*32 + quad*8);
                short8 bb = *(const short8*)(B + (nt*16 + m)*STR + k*32 + quad*8);
                sc[nt] = __builtin_amdgcn_mfma_f32_16x16x32_bf16(a, bb, sc[nt], 0,0,0);
            }
    };
    auto scoreDump = [&](const f32x4* sc, ushort_t* dst) {
        int c0 = wv*16 + quad*4;
#pragma unroll
        for (int nt = 0; nt < 4; ++nt) {
            int d = nt*16 + m;
#pragma unroll
            for (int r = 0; r < 4; ++r) dst[(c0 + r)*STR + d] = f2bf(sc[nt][r]);
        }
    };
    auto feat = [&](const ushort_t* Sc, const ushort_t* XpT, ushort_t* stg) {
        int mt = wv;
#pragma unroll
        for (int nt = 0; nt < 4; ++nt) {
            f32x4 acc = {0.f,0.f,0.f,0.f};
#pragma unroll
            for (int k = 0; k < 2; ++k) {
                short8 a  = *(const short8*)(Sc  + (mt*16 + m)*STR + k*32 + quad*8);
                short8 bb = *(const short8*)(XpT + (nt*16 + m)*STR + k*32 + quad*8);
                acc = __builtin_amdgcn_mfma_f32_16x16x32_bf16(a, bb, acc, 0,0,0);
            }
            int w = nt*16 + m, c0 = mt*16 + quad*4;
            *(int*)(stg + w*STR + c0)     = pack2(f2bf(acc[0]), f2bf(acc[1]));
            *(int*)(stg + w*STR + c0 + 2) = pack2(f2bf(acc[2]), f2bf(acc[3]));
        }
    };
    auto emitBr = [&](const ushort_t* stg, int wc, int coff) {
#pragma unroll
        for (int it = 0; it < 2; ++it) {
            int j = it*256 + t;
            int row = j >> 3, seg = j & 7;
            int v[4];
#pragma unroll
            for (int k = 0; k < 4; ++k) v[k] = *(const int*)(stg + row*STR + seg*8 + k*2);
            ushort_t* dst = inT2 + (((size_t)b*PW + h + 1)*PW + (wc + 1 + row))*ICS
                                 + coff + seg*8;
            *(int4*)dst = make_int4(v[0], v[1], v[2], v[3]);
        }
    };

    const ushort_t* W0 = Wall;            const float* b0 = ball;
    const ushort_t* W1 = Wall + 4096;     const float* b1 = ball + 64;
    const ushort_t* W2 = Wall + 2*4096;   const float* b2 = ball + 128;
    const ushort_t* W3 = Wall + 3*4096;   const float* b3 = ball + 192;
    const ushort_t* W4 = Wall + 4*4096;   const float* b4 = ball + 256;

    f32x4 sc1[4], sc2[4];
#pragma unroll
    for (int i = 0; i < 4; ++i) { sc1[i] = (f32x4){0,0,0,0}; sc2[i] = (f32x4){0,0,0,0}; }

    for (int wc = 0; wc < WD; wc += 64) {
        stage(xs, wc, P);            __syncthreads();
        projB(P, W1, b1, R);         stage(xfs, wc, Q);   __syncthreads();
        projB(Q, W3, b3, T);         __syncthreads();
        scoreStep(R, T, sc1);        stage(xrs, wc, Q);   __syncthreads();
        projB(P, W2, b2, R);         projB(Q, W4, b4, T); __syncthreads();
        scoreStep(R, T, sc2);        __syncthreads();
    }

    scoreDump(sc1, P);  scoreDump(sc2, R);  __syncthreads();
    for (int wc = 0; wc < WD; wc += 64) {
        stage(xs, wc, Q);            __syncthreads();
        projA(Q, W0, b0, T);         __syncthreads();
        feat(P, T, Q);               __syncthreads();
        emitBr(Q, wc, 0);            __syncthreads();
        feat(R, T, Q);               __syncthreads();
        emitBr(Q, wc, 64);           __syncthreads();
    }
}

// ===========================================================================
// prep kernel: x -> inT2[...][128..191] bf16 (channel-last) + zero all halos.
// ===========================================================================
__global__ __launch_bounds__(256) void prep_kernel(const float* __restrict__ x,
                                                   ushort_t* __restrict__ inT2)
{
    int b  = blockIdx.x / PW, py = blockIdx.x % PW;
    int t  = threadIdx.x;
    ushort_t* rowp = inT2 + ((size_t)b*PW + py)*(size_t)PW*ICS;

    if (py == 0 || py == PW-1) {
        int4 z = make_int4(0,0,0,0);
        for (int j = t; j < PW*ICS/8; j += 256) ((int4*)rowp)[j] = z;
        return;
    }
    if (t < 48) {
        int side = t / 24, seg = t % 24;
        ((int4*)(rowp + (size_t)(side ? (PW-1) : 0)*ICS))[seg] = make_int4(0,0,0,0);
    }
    __shared__ ushort_t sx[128*72];
    int y = py - 1;
    for (int k = t; k < 64*128; k += 256) {
        int c = k >> 7, xx = k & 127;
        sx[xx*72 + c] = f2bf(x[((size_t)b*C + c)*HW + (size_t)y*WD + xx]);
    }
    __syncthreads();
    for (int j = t; j < 128*8; j += 256) {
        int xx = j >> 3, seg = j & 7;
        *(int4*)(rowp + (size_t)(xx+1)*ICS + 128 + seg*8) = *(const int4*)(sx + xx*72 + seg*8);
    }
}

// ===========================================================================
// weight pack for conv: W_msa -> Wpack[otile][tap*6+icc][lane][8] bf16.
// ===========================================================================
__global__ __launch_bounds__(256) void pack_kernel(const float* __restrict__ W,
                                                   ushort_t* __restrict__ Wpk)
{
    int k = blockIdx.x*256 + threadIdx.x;
    if (k >= 12*54*64) return;
    int lane = k & 63, os = k >> 6;
    int otile = os / 54, s = os % 54;
    int tap = s / 6, icc = s % 6;
    int o   = otile*16 + (lane & 15);
    int ic0 = icc*32 + (lane >> 4)*8;
    ushort_t v[8];
#pragma unroll
    for (int j = 0; j < 8; ++j)
        v[j] = f2bf(W[(size_t)(o*C3 + ic0 + j)*9 + tap]);
    *(int4*)(Wpk + (size_t)k*8) = *(const int4*)v;
}

// ===========================================================================
// conv v2: implicit-GEMM bf16 MFMA, full 192-o per block.
// Block = (b, y-pair), 512 threads = 8 waves: wave = (og 0..3, yi 0..1).
// Wave owns 3 o-tiles x 8 x-tiles x 1 y = 24 accum tiles (96 VGPR).
// Staging: 4 rows x 130 gx x 32 c bf16 (33,280 B, single LDS buffer) with
// REGISTER double-buffer: next icc chunk loaded to VGPRs during MFMA phase,
// ds_write after the read-barrier. B-frags pipelined across taps (L2 hiding).
// Input HBM traffic: 512 blocks x 200 KB = 105 MB (was 311 MB demand).
// ===========================================================================
__global__ __launch_bounds__(512, 2) void conv_mfma(
    const ushort_t* __restrict__ inT2, const ushort_t* __restrict__ Wpk,
    const float* __restrict__ bias, const float* __restrict__ gamma,
    const float* __restrict__ beta, const float* __restrict__ mean,
    const float* __restrict__ var,  float* __restrict__ out)
{
    __shared__ ushort_t sIn[4*PW*32];          // 33,280 B

    const int t = threadIdx.x;
    const int wv = t >> 6, lane = t & 63;
    const int m = lane & 15, quad = lane >> 4;
    const int b  = blockIdx.x >> 6, y0 = (blockIdx.x & 63)*2;
    const int yi = wv & 1, og = wv >> 1;       // og: 3 o-tiles each

    f32x4 acc[24];                              // [xt][j] -> acc[xt*3+j]
#pragma unroll
    for (int i = 0; i < 24; ++i) acc[i] = (f32x4){0.f,0.f,0.f,0.f};

    // --- staging helpers: 2080 16B slots; 512 thr x 4 + 32-thread tail ---
    auto loadRegs = [&](int icc, int4* pf) {
#pragma unroll
        for (int i = 0; i < 4; ++i) {
            int sl = i*512 + t;
            int wi = sl & 3, rowgx = sl >> 2;
            int row = rowgx / PW, gx = rowgx - row*PW;
            pf[i] = *(const int4*)(inT2 + (((size_t)b*PW + y0 + row)*PW + gx)*ICS
                                        + icc*32 + wi*8);
        }
        if (t < 32) {
            int sl = 2048 + t;
            int wi = sl & 3, rowgx = sl >> 2;
            int row = rowgx / PW, gx = rowgx - row*PW;
            pf[4] = *(const int4*)(inT2 + (((size_t)b*PW + y0 + row)*PW + gx)*ICS
                                        + icc*32 + wi*8);
        }
    };
    auto writeLDS = [&](const int4* pf) {
#pragma unroll
        for (int i = 0; i < 4; ++i) *(int4*)(sIn + ((size_t)(i*512 + t))*8) = pf[i];
        if (t < 32) *(int4*)(sIn + ((size_t)(2048 + t))*8) = pf[4];
    };
    // --- compute one icc chunk: 9 taps, bf pipelined one tap ahead ---
    auto compute = [&](int icc) {
        short8 bf[3], bfn[3];
#pragma unroll
        for (int j = 0; j < 3; ++j)
            bf[j] = *(const short8*)(Wpk + (((size_t)(og*3+j)*54 + icc)*64 + lane)*8);
#pragma unroll
        for (int tap = 0; tap < 9; ++tap) {
            if (tap < 8) {
#pragma unroll
                for (int j = 0; j < 3; ++j)
                    bfn[j] = *(const short8*)(Wpk + (((size_t)(og*3+j)*54
                                              + (tap+1)*6 + icc)*64 + lane)*8);
            }
            const int ky = tap / 3, kx = tap % 3;
            const int rb = ((yi + ky)*PW + kx + m)*32 + quad*8;
#pragma unroll
            for (int xt = 0; xt < 8; ++xt) {
                short8 af = *(const short8*)(sIn + rb + xt*512);
                acc[xt*3+0] = __builtin_amdgcn_mfma_f32_16x16x32_bf16(af, bf[0], acc[xt*3+0], 0,0,0);
                acc[xt*3+1] = __builtin_amdgcn_mfma_f32_16x16x32_bf16(af, bf[1], acc[xt*3+1], 0,0,0);
                acc[xt*3+2] = __builtin_amdgcn_mfma_f32_16x16x32_bf16(af, bf[2], acc[xt*3+2], 0,0,0);
            }
#pragma unroll
            for (int j = 0; j < 3; ++j) bf[j] = bfn[j];
        }
    };

    int4 pf[5];
    loadRegs(0, pf);
    writeLDS(pf);
    __syncthreads();
    for (int icc = 0; icc < 6; ++icc) {
        if (icc < 5) loadRegs(icc + 1, pf);    // HBM->reg overlaps MFMA below
        compute(icc);
        __syncthreads();                       // all waves done reading sIn
        if (icc < 5) { writeLDS(pf); __syncthreads(); }
    }

    // --- epilogue: bias + BN(eval, eps=1e-4) + ReLU, fp32 out ---
    const int y = y0 + yi;
#pragma unroll
    for (int j = 0; j < 3; ++j) {
        int o = (og*3 + j)*16 + m;
        float A  = gamma[o] * rsqrtf(var[o] + 1e-4f);
        float Bv = (bias[o] - mean[o])*A + beta[o];
        float* orow = out + (((size_t)b*C3 + o)*H + y)*WD;
#pragma unroll
        for (int xt = 0; xt < 8; ++xt) {
            f32x4 a4 = acc[xt*3 + j];
            float4 v = make_float4(fmaxf(a4[0]*A + Bv, 0.f), fmaxf(a4[1]*A + Bv, 0.f),
                                   fmaxf(a4[2]*A + Bv, 0.f), fmaxf(a4[3]*A + Bv, 0.f));
            *(float4*)(orow + xt*16 + quad*4) = v;
        }
    }
}

extern "C" void kernel_launch(void* const* d_in, const int* in_sizes, int n_in,
                              void* d_out, int out_size, void* d_ws, size_t ws_size,
                              hipStream_t stream)
{
    const float* x   = (const float*)d_in[0];
    const float* xf  = (const float*)d_in[1];
    const float* xr  = (const float*)d_in[2];
    const float* Wx  = (const float*)d_in[3];
    const float* bx  = (const float*)d_in[4];
    const float* Wx1 = (const float*)d_in[5];
    const float* bx1 = (const float*)d_in[6];
    const float* Wx2 = (const float*)d_in[7];
    const float* bx2 = (const float*)d_in[8];
    const float* Wxf = (const float*)d_in[9];
    const float* bxf = (const float*)d_in[10];
    const float* Wxr = (const float*)d_in[11];
    const float* bxr = (const float*)d_in[12];
    const float* Wm  = (const float*)d_in[13];
    const float* bms = (const float*)d_in[14];
    const float* gam = (const float*)d_in[15];
    const float* bet = (const float*)d_in[16];
    const float* mea = (const float*)d_in[17];
    const float* va  = (const float*)d_in[18];
    (void)in_sizes; (void)n_in; (void)out_size; (void)ws_size;

    // ws layout: inT2 (B,130,130,192) bf16 @ 0 (51,916,800 B);
    //            conv Wpack @ 52,000,000 (663,552 B);
    //            attn Wall bf16 @ 52,700,000; ball f32 @ 52,750,000.
    ushort_t* inT2 = (ushort_t*)d_ws;
    ushort_t* Wpk  = (ushort_t*)((char*)d_ws + 52000000);
    ushort_t* Wall = (ushort_t*)((char*)d_ws + 52700000);
    float*    ball = (float*)   ((char*)d_ws + 52750000);
    float* outp = (float*)d_out;

    compose_kernel<<<dim3(1), dim3(256), 0, stream>>>(
        Wx, bx, Wx1, bx1, Wx2, bx2, Wxf, bxf, Wxr, bxr, Wall, ball);
    pack_kernel<<<dim3(162), dim3(256), 0, stream>>>(Wm, Wpk);
    prep_kernel<<<dim3(BATCH*PW), dim3(256), 0, stream>>>(x, inT2);
    attn_mfma<<<dim3(BATCH*H), dim3(256), 0, stream>>>(
        x, xf, xr, Wall, ball, inT2);
    conv_mfma<<<dim3(BATCH*64), dim3(512), 0, stream>>>(
        inT2, Wpk, bms, gam, bet, mea, va, outp);
}

// Round 5
// 458.378 us; speedup vs baseline: 6.1381x; 1.0586x over previous
//
#include <hip/hip_runtime.h>

#define BATCH 8
#define C     64
#define H     128
#define WD    128
#define C3    192
#define HW    (H*WD)
#define PW    130         // padded H/W for conv input
#define ICS   192         // channel stride in inT2 (channel-last)
#define STR   72          // attn LDS row stride in shorts
#define CBUF  (4*PW*64)   // conv stage buffer: 4 rows x 130 gx x 64 c (shorts)

typedef __attribute__((ext_vector_type(8))) short short8;
typedef __attribute__((ext_vector_type(4))) float f32x4;
typedef unsigned short ushort_t;

__device__ __forceinline__ unsigned short f2bf(float f) {
    unsigned u = __builtin_bit_cast(unsigned, f);
    u += 0x7fffu + ((u >> 16) & 1u);
    return (unsigned short)(u >> 16);
}
__device__ __forceinline__ int pack2(unsigned short lo, unsigned short hi) {
    return (int)(((unsigned)hi << 16) | (unsigned)lo);
}

// ===========================================================================
// compose_kernel: fold Wx into Wx1/Wx2; pack 5 weight mats to bf16 + biases.
// ===========================================================================
__global__ __launch_bounds__(256) void compose_kernel(
    const float* __restrict__ Wx,  const float* __restrict__ bx,
    const float* __restrict__ Wx1, const float* __restrict__ bx1,
    const float* __restrict__ Wx2, const float* __restrict__ bx2,
    const float* __restrict__ Wxf, const float* __restrict__ bxf,
    const float* __restrict__ Wxr, const float* __restrict__ bxr,
    ushort_t* __restrict__ Wall, float* __restrict__ ball)
{
    int t = threadIdx.x;
    int o = t & 63, cq = t >> 6;
    for (int c = cq*16; c < cq*16 + 16; ++c) {
        Wall[0*4096 + o*64 + c] = f2bf(Wx [o*64 + c]);
        Wall[3*4096 + o*64 + c] = f2bf(Wxf[o*64 + c]);
        Wall[4*4096 + o*64 + c] = f2bf(Wxr[o*64 + c]);
        float a1 = 0.f, a2 = 0.f;
        for (int k = 0; k < 64; ++k) {
            float wc = Wx[k*64 + c];
            a1 += Wx1[o*64 + k] * wc;
            a2 += Wx2[o*64 + k] * wc;
        }
        Wall[1*4096 + o*64 + c] = f2bf(a1);
        Wall[2*4096 + o*64 + c] = f2bf(a2);
    }
    if (cq == 0) {
        ball[0*64 + o] = bx[o];
        ball[3*64 + o] = bxf[o];
        ball[4*64 + o] = bxr[o];
        float b1 = bx1[o], b2 = bx2[o];
        for (int k = 0; k < 64; ++k) {
            b1 += Wx1[o*64 + k] * bx[k];
            b2 += Wx2[o*64 + k] * bx[k];
        }
        ball[1*64 + o] = b1;
        ball[2*64 + o] = b2;
    }
}

// ===========================================================================
// attn_mfma: one block per (b,h), 256 threads = 4 waves (unchanged from R3).
// ===========================================================================
__global__ __launch_bounds__(256, 4) void attn_mfma(
    const float* __restrict__ x, const float* __restrict__ xf, const float* __restrict__ xr,
    const ushort_t* __restrict__ Wall, const float* __restrict__ ball,
    ushort_t* __restrict__ inT2)
{
    __shared__ ushort_t lds[4*64*STR];
    ushort_t* P = lds;
    ushort_t* Q = lds + 64*STR;
    ushort_t* R = lds + 2*64*STR;
    ushort_t* T = lds + 3*64*STR;

    const int t = threadIdx.x;
    const int wv = t >> 6, lane = t & 63, m = lane & 15, quad = lane >> 4;
    const int b = blockIdx.x >> 7, h = blockIdx.x & 127;
    const float* xs  = x  + (size_t)b*C*HW + (size_t)h*WD;
    const float* xfs = xf + (size_t)b*C*HW + (size_t)h*WD;
    const float* xrs = xr + (size_t)b*C*HW + (size_t)h*WD;

    auto stage = [&](const float* src, int wc, ushort_t* dst) {
        int c = t >> 2, wq = (t & 3) << 4;
        const float* p = src + (size_t)c*HW + wc + wq;
        float4 v0 = *(const float4*)(p);
        float4 v1 = *(const float4*)(p + 4);
        float4 v2 = *(const float4*)(p + 8);
        float4 v3 = *(const float4*)(p + 12);
        float vv[16] = {v0.x,v0.y,v0.z,v0.w, v1.x,v1.y,v1.z,v1.w,
                        v2.x,v2.y,v2.z,v2.w, v3.x,v3.y,v3.z,v3.w};
#pragma unroll
        for (int j = 0; j < 16; ++j) dst[(wq + j)*STR + c] = f2bf(vv[j]);
    };
    auto projB = [&](const ushort_t* src, const ushort_t* W, const float* bias,
                     ushort_t* dst) {
        int mt = wv;
#pragma unroll
        for (int nt = 0; nt < 4; ++nt) {
            f32x4 acc = {0.f,0.f,0.f,0.f};
#pragma unroll
            for (int k = 0; k < 2; ++k) {
                short8 a  = *(const short8*)(src + (mt*16 + m)*STR + k*32 + quad*8);
                short8 bb = *(const short8*)(W   + (nt*16 + m)*64  + k*32 + quad*8);
                acc = __builtin_amdgcn_mfma_f32_16x16x32_bf16(a, bb, acc, 0,0,0);
            }
            float bo = bias[nt*16 + m];
            int o = nt*16 + m, w0 = mt*16 + quad*4;
            *(int*)(dst + o*STR + w0)     = pack2(f2bf(acc[0]+bo), f2bf(acc[1]+bo));
            *(int*)(dst + o*STR + w0 + 2) = pack2(f2bf(acc[2]+bo), f2bf(acc[3]+bo));
        }
    };
    auto projA = [&](const ushort_t* src, const ushort_t* W, const float* bias,
                     ushort_t* dstT) {
        int mt = wv;
        float b4[4];
#pragma unroll
        for (int r = 0; r < 4; ++r) b4[r] = bias[mt*16 + quad*4 + r];
#pragma unroll
        for (int nt = 0; nt < 4; ++nt) {
            f32x4 acc = {0.f,0.f,0.f,0.f};
#pragma unroll
            for (int k = 0; k < 2; ++k) {
                short8 a  = *(const short8*)(W   + (mt*16 + m)*64  + k*32 + quad*8);
                short8 bb = *(const short8*)(src + (nt*16 + m)*STR + k*32 + quad*8);
                acc = __builtin_amdgcn_mfma_f32_16x16x32_bf16(a, bb, acc, 0,0,0);
            }
            int w = nt*16 + m, o0 = mt*16 + quad*4;
            *(int*)(dstT + w*STR + o0)     = pack2(f2bf(acc[0]+b4[0]), f2bf(acc[1]+b4[1]));
            *(int*)(dstT + w*STR + o0 + 2) = pack2(f2bf(acc[2]+b4[2]), f2bf(acc[3]+b4[3]));
        }
    };
    auto scoreStep = [&](const ushort_t* A, const ushort_t* B, f32x4* sc) {
        int mt = wv;
#pragma unroll
        for (int nt = 0; nt < 4; ++nt)
#pragma unroll
            for (int k = 0; k < 2; ++k) {
                short8 a  = *(const short8*)(A + (mt*16 + m)*STR + k*32 + quad*8);
                short8 bb = *(const short8*)(B + (nt*16 + m)*STR + k*32 + quad*8);
                sc[nt] = __builtin_amdgcn_mfma_f32_16x16x32_bf16(a, bb, sc[nt], 0,0,0);
            }
    };
    auto scoreDump = [&](const f32x4* sc, ushort_t* dst) {
        int c0 = wv*16 + quad*4;
#pragma unroll
        for (int nt = 0; nt < 4; ++nt) {
            int d = nt*16 + m;
#pragma unroll
            for (int r = 0; r < 4; ++r) dst[(c0 + r)*STR + d] = f2bf(sc[nt][r]);
        }
    };
    auto feat = [&](const ushort_t* Sc, const ushort_t* XpT, ushort_t* stg) {
        int mt = wv;
#pragma unroll
        for (int nt = 0; nt < 4; ++nt) {
            f32x4 acc = {0.f,0.f,0.f,0.f};
#pragma unroll
            for (int k = 0; k < 2; ++k) {
                short8 a  = *(const short8*)(Sc  + (mt*16 + m)*STR + k*32 + quad*8);
                short8 bb = *(const short8*)(XpT + (nt*16 + m)*STR + k*32 + quad*8);
                acc = __builtin_amdgcn_mfma_f32_16x16x32_bf16(a, bb, acc, 0,0,0);
            }
            int w = nt*16 + m, c0 = mt*16 + quad*4;
            *(int*)(stg + w*STR + c0)     = pack2(f2bf(acc[0]), f2bf(acc[1]));
            *(int*)(stg + w*STR + c0 + 2) = pack2(f2bf(acc[2]), f2bf(acc[3]));
        }
    };
    auto emitBr = [&](const ushort_t* stg, int wc, int coff) {
#pragma unroll
        for (int it = 0; it < 2; ++it) {
            int j = it*256 + t;
            int row = j >> 3, seg = j & 7;
            int v[4];
#pragma unroll
            for (int k = 0; k < 4; ++k) v[k] = *(const int*)(stg + row*STR + seg*8 + k*2);
            ushort_t* dst = inT2 + (((size_t)b*PW + h + 1)*PW + (wc + 1 + row))*ICS
                                 + coff + seg*8;
            *(int4*)dst = make_int4(v[0], v[1], v[2], v[3]);
        }
    };

    const ushort_t* W0 = Wall;            const float* b0 = ball;
    const ushort_t* W1 = Wall + 4096;     const float* b1 = ball + 64;
    const ushort_t* W2 = Wall + 2*4096;   const float* b2 = ball + 128;
    const ushort_t* W3 = Wall + 3*4096;   const float* b3 = ball + 192;
    const ushort_t* W4 = Wall + 4*4096;   const float* b4 = ball + 256;

    f32x4 sc1[4], sc2[4];
#pragma unroll
    for (int i = 0; i < 4; ++i) { sc1[i] = (f32x4){0,0,0,0}; sc2[i] = (f32x4){0,0,0,0}; }

    for (int wc = 0; wc < WD; wc += 64) {
        stage(xs, wc, P);            __syncthreads();
        projB(P, W1, b1, R);         stage(xfs, wc, Q);   __syncthreads();
        projB(Q, W3, b3, T);         __syncthreads();
        scoreStep(R, T, sc1);        stage(xrs, wc, Q);   __syncthreads();
        projB(P, W2, b2, R);         projB(Q, W4, b4, T); __syncthreads();
        scoreStep(R, T, sc2);        __syncthreads();
    }

    scoreDump(sc1, P);  scoreDump(sc2, R);  __syncthreads();
    for (int wc = 0; wc < WD; wc += 64) {
        stage(xs, wc, Q);            __syncthreads();
        projA(Q, W0, b0, T);         __syncthreads();
        feat(P, T, Q);               __syncthreads();
        emitBr(Q, wc, 0);            __syncthreads();
        feat(R, T, Q);               __syncthreads();
        emitBr(Q, wc, 64);           __syncthreads();
    }
}

// ===========================================================================
// prep kernel: x -> inT2[...][128..191] bf16 (channel-last) + zero all halos.
// ===========================================================================
__global__ __launch_bounds__(256) void prep_kernel(const float* __restrict__ x,
                                                   ushort_t* __restrict__ inT2)
{
    int b  = blockIdx.x / PW, py = blockIdx.x % PW;
    int t  = threadIdx.x;
    ushort_t* rowp = inT2 + ((size_t)b*PW + py)*(size_t)PW*ICS;

    if (py == 0 || py == PW-1) {
        int4 z = make_int4(0,0,0,0);
        for (int j = t; j < PW*ICS/8; j += 256) ((int4*)rowp)[j] = z;
        return;
    }
    if (t < 48) {
        int side = t / 24, seg = t % 24;
        ((int4*)(rowp + (size_t)(side ? (PW-1) : 0)*ICS))[seg] = make_int4(0,0,0,0);
    }
    __shared__ ushort_t sx[128*72];
    int y = py - 1;
    for (int k = t; k < 64*128; k += 256) {
        int c = k >> 7, xx = k & 127;
        sx[xx*72 + c] = f2bf(x[((size_t)b*C + c)*HW + (size_t)y*WD + xx]);
    }
    __syncthreads();
    for (int j = t; j < 128*8; j += 256) {
        int xx = j >> 3, seg = j & 7;
        *(int4*)(rowp + (size_t)(xx+1)*ICS + 128 + seg*8) = *(const int4*)(sx + xx*72 + seg*8);
    }
}

// ===========================================================================
// weight pack for conv: W_msa -> Wpack[otile][tap*6+icc][lane][8] bf16.
// ===========================================================================
__global__ __launch_bounds__(256) void pack_kernel(const float* __restrict__ W,
                                                   ushort_t* __restrict__ Wpk)
{
    int k = blockIdx.x*256 + threadIdx.x;
    if (k >= 12*54*64) return;
    int lane = k & 63, os = k >> 6;
    int otile = os / 54, s = os % 54;
    int tap = s / 6, icc = s % 6;
    int o   = otile*16 + (lane & 15);
    int ic0 = icc*32 + (lane >> 4)*8;
    ushort_t v[8];
#pragma unroll
    for (int j = 0; j < 8; ++j)
        v[j] = f2bf(W[(size_t)(o*C3 + ic0 + j)*9 + tap]);
    *(int4*)(Wpk + (size_t)k*8) = *(const int4*)v;
}

// ===========================================================================
// conv v3: producer-consumer implicit-GEMM bf16 MFMA.
// Block = (b, y-pair), 512 threads = 8 waves: waves 0..5 compute
// (og=wv>>1 owns 4 o-tiles, yi=wv&1 owns a row), waves 6..7 produce.
// LDS: double buffer [4 rows][130 gx][64 c] bf16 = 2 x 66,560 B (gfx950 160KB).
// Producers stage chunk k+1 via global_load_lds while consumers crunch chunk k
// (per-wave vmcnt -> no cross-wave drains). A-granules XOR-swizzled by gx&7
// (applied on the producer's GLOBAL address; LDS side stays uniform+lane*16)
// -> conflict-free ds_read_b128. Epilogue stages BN+ReLU rows in LDS then
// writes full 512B lines.
// ===========================================================================
__global__ __launch_bounds__(512, 2) void conv_mfma(
    const ushort_t* __restrict__ inT2, const ushort_t* __restrict__ Wpk,
    const float* __restrict__ bias, const float* __restrict__ gamma,
    const float* __restrict__ beta, const float* __restrict__ mean,
    const float* __restrict__ var,  float* __restrict__ out)
{
    __shared__ ushort_t sA[2*CBUF];            // 133,120 B

    const int t = threadIdx.x;
    const int wv = t >> 6, lane = t & 63;
    const int m = lane & 15, quad = lane >> 4;
    const int b  = blockIdx.x >> 6, y0 = (blockIdx.x & 63)*2;
    const int yi = wv & 1, og = wv >> 1;       // compute waves: og 0..2

    f32x4 acc[32];                              // [j][xt] -> acc[j*8+xt]
#pragma unroll
    for (int i = 0; i < 32; ++i) acc[i] = (f32x4){0.f,0.f,0.f,0.f};

    // ---- producer: stage 64-c chunk into buffer (4160 16B slots, 128 lanes)
    auto produce = [&](int ch, int bufi) {
        ushort_t* dst = sA + bufi*CBUF;
        const int ic0 = ch*64;
        const int pt = t - 384;                // wave 6 -> 0..63, wave 7 -> 64..127
        for (int i = 0; i < 32; ++i) {
            int sl = i*128 + pt;
            int wi = sl & 7, rowgx = sl >> 3;
            int row = rowgx / PW, gx = rowgx - row*PW;
            int wl = wi ^ (gx & 7);            // granule swizzle (global side)
            const ushort_t* g = inT2 + (((size_t)b*PW + y0 + row)*PW + gx)*ICS
                                     + ic0 + wl*8;
            __builtin_amdgcn_global_load_lds(
                (const __attribute__((address_space(1))) unsigned int*)g,
                (__attribute__((address_space(3))) unsigned int*)(dst + (size_t)sl*8),
                16, 0, 0);
        }
        if (pt < 64) {
            int sl = 4096 + pt;
            int wi = sl & 7, rowgx = sl >> 3;
            int row = rowgx / PW, gx = rowgx - row*PW;
            int wl = wi ^ (gx & 7);
            const ushort_t* g = inT2 + (((size_t)b*PW + y0 + row)*PW + gx)*ICS
                                     + ic0 + wl*8;
            __builtin_amdgcn_global_load_lds(
                (const __attribute__((address_space(1))) unsigned int*)g,
                (__attribute__((address_space(3))) unsigned int*)(dst + (size_t)sl*8),
                16, 0, 0);
        }
    };

    // ---- consumer: one 64-c chunk = 9 taps x 8 xt x 2 k x 4 o-tiles ----
    auto compute = [&](int ch, int bufi) {
        const ushort_t* src = sA + bufi*CBUF;
        short8 bf[8], bfn[8];
#pragma unroll
        for (int j = 0; j < 4; ++j)
#pragma unroll
            for (int k = 0; k < 2; ++k)
                bf[j*2+k] = *(const short8*)(Wpk +
                    (((size_t)(og*4+j)*54 + ch*2 + k)*64 + lane)*8);
#pragma unroll
        for (int tap = 0; tap < 9; ++tap) {
            if (tap < 8) {
#pragma unroll
                for (int j = 0; j < 4; ++j)
#pragma unroll
                    for (int k = 0; k < 2; ++k)
                        bfn[j*2+k] = *(const short8*)(Wpk +
                            (((size_t)(og*4+j)*54 + (tap+1)*6 + ch*2 + k)*64 + lane)*8);
            }
            const int ky = tap/3, kx = tap - ky*3;
            const int sw = (kx + m) & 7;
            const int rowb = ((yi + ky)*PW + kx + m)*64;
            const int g0 = (quad ^ sw)*8, g1 = ((quad+4) ^ sw)*8;
#pragma unroll
            for (int xt = 0; xt < 8; ++xt) {
                short8 af0 = *(const short8*)(src + rowb + xt*1024 + g0);
                short8 af1 = *(const short8*)(src + rowb + xt*1024 + g1);
#pragma unroll
                for (int j = 0; j < 4; ++j) {
                    acc[j*8+xt] = __builtin_amdgcn_mfma_f32_16x16x32_bf16(af0, bf[j*2],   acc[j*8+xt], 0,0,0);
                    acc[j*8+xt] = __builtin_amdgcn_mfma_f32_16x16x32_bf16(af1, bf[j*2+1], acc[j*8+xt], 0,0,0);
                }
            }
#pragma unroll
            for (int q = 0; q < 8; ++q) bf[q] = bfn[q];
        }
    };

    // ---- pipeline: 3 chunks of 64 c, producers one chunk ahead ----
    if (wv >= 6) produce(0, 0);
    __syncthreads();
    for (int ch = 0; ch < 3; ++ch) {
        if (wv >= 6) { if (ch < 2) produce(ch + 1, (ch + 1) & 1); }
        else          compute(ch, ch & 1);
        __syncthreads();
    }

    // ---- epilogue: BN+ReLU -> LDS stage -> full-line stores ----
    float* sOut = (float*)sA;                  // 192 x 132 f32 = 101,376 B
    for (int y = 0; y < 2; ++y) {
        if (wv < 6 && yi == y) {
#pragma unroll
            for (int j = 0; j < 4; ++j) {
                int o = (og*4 + j)*16 + m;
                float A  = gamma[o] * rsqrtf(var[o] + 1e-4f);
                float Bv = (bias[o] - mean[o])*A + beta[o];
#pragma unroll
                for (int xt = 0; xt < 8; ++xt) {
                    f32x4 a4 = acc[j*8 + xt];
                    *(float4*)(sOut + o*132 + xt*16 + quad*4) =
                        make_float4(fmaxf(a4[0]*A + Bv, 0.f), fmaxf(a4[1]*A + Bv, 0.f),
                                    fmaxf(a4[2]*A + Bv, 0.f), fmaxf(a4[3]*A + Bv, 0.f));
                }
            }
        }
        __syncthreads();
#pragma unroll
        for (int i = 0; i < 12; ++i) {
            int s = i*512 + t;                 // 6144 float4 slots
            int o = s >> 5, xs4 = (s & 31)*4;
            float4 v = *(const float4*)(sOut + o*132 + xs4);
            *(float4*)(out + (((size_t)b*C3 + o)*H + y0 + y)*WD + xs4) = v;
        }
        __syncthreads();
    }
}

extern "C" void kernel_launch(void* const* d_in, const int* in_sizes, int n_in,
                              void* d_out, int out_size, void* d_ws, size_t ws_size,
                              hipStream_t stream)
{
    const float* x   = (const float*)d_in[0];
    const float* xf  = (const float*)d_in[1];
    const float* xr  = (const float*)d_in[2];
    const float* Wx  = (const float*)d_in[3];
    const float* bx  = (const float*)d_in[4];
    const float* Wx1 = (const float*)d_in[5];
    const float* bx1 = (const float*)d_in[6];
    const float* Wx2 = (const float*)d_in[7];
    const float* bx2 = (const float*)d_in[8];
    const float* Wxf = (const float*)d_in[9];
    const float* bxf = (const float*)d_in[10];
    const float* Wxr = (const float*)d_in[11];
    const float* bxr = (const float*)d_in[12];
    const float* Wm  = (const float*)d_in[13];
    const float* bms = (const float*)d_in[14];
    const float* gam = (const float*)d_in[15];
    const float* bet = (const float*)d_in[16];
    const float* mea = (const float*)d_in[17];
    const float* va  = (const float*)d_in[18];
    (void)in_sizes; (void)n_in; (void)out_size; (void)ws_size;

    // ws layout: inT2 (B,130,130,192) bf16 @ 0 (51,916,800 B);
    //            conv Wpack @ 52,000,000 (663,552 B);
    //            attn Wall bf16 @ 52,700,000; ball f32 @ 52,750,000.
    ushort_t* inT2 = (ushort_t*)d_ws;
    ushort_t* Wpk  = (ushort_t*)((char*)d_ws + 52000000);
    ushort_t* Wall = (ushort_t*)((char*)d_ws + 52700000);
    float*    ball = (float*)   ((char*)d_ws + 52750000);
    float* outp = (float*)d_out;

    compose_kernel<<<dim3(1), dim3(256), 0, stream>>>(
        Wx, bx, Wx1, bx1, Wx2, bx2, Wxf, bxf, Wxr, bxr, Wall, ball);
    pack_kernel<<<dim3(162), dim3(256), 0, stream>>>(Wm, Wpk);
    prep_kernel<<<dim3(BATCH*PW), dim3(256), 0, stream>>>(x, inT2);
    attn_mfma<<<dim3(BATCH*H), dim3(256), 0, stream>>>(
        x, xf, xr, Wall, ball, inT2);
    conv_mfma<<<dim3(BATCH*64), dim3(512), 0, stream>>>(
        inT2, Wpk, bms, gam, bet, mea, va, outp);
}